// Round 1
// 424.308 us; speedup vs baseline: 1.0381x; 1.0381x over previous
//
#include <hip/hip_runtime.h>

typedef unsigned short u16;
typedef unsigned int u32;

constexpr int Bc = 2, Sc = 2048, Dc = 2048, Hc = 16, HDc = 128;

using short8 = __attribute__((ext_vector_type(8))) short;
using f32x4v = __attribute__((ext_vector_type(4))) float;

static __device__ __forceinline__ float bf2f(u16 v) { return __uint_as_float(((u32)v) << 16); }
static __device__ __forceinline__ u16 f2bf(float f) {
    u32 u = __float_as_uint(f);
    return (u16)((u + 0x7fffu + ((u >> 16) & 1u)) >> 16);
}

// async global->LDS, 16B per lane; LDS dest = wave-uniform base + lane*16
__device__ __forceinline__ void gll16(const u16* g, u16* l) {
    __builtin_amdgcn_global_load_lds((const __attribute__((address_space(1))) void*)g,
                                     (__attribute__((address_space(3))) void*)l, 16, 0, 0);
}

// ---------------- RoPE cos/sin tables: [S][64] fp32 ----------------
__global__ __launch_bounds__(256) void rope_tab_k(float* __restrict__ ctab, float* __restrict__ stab) {
    int idx = blockIdx.x * 256 + threadIdx.x; // S*64 threads
    int s = idx >> 6, i = idx & 63;
    float freq = exp2f(-(float)i * 0.20762050593045952f); // 10000^(-i/64)
    float ang = (float)s * freq;
    float c, sn;
    sincosf(ang, &sn, &c);
    ctab[idx] = c;
    stab[idx] = sn;
}

// ---------------- fp32 -> bf16 bulk convert ----------------
__global__ __launch_bounds__(256) void cvt_k(const float* __restrict__ in, u16* __restrict__ out, int n) {
    int i = (blockIdx.x * 256 + threadIdx.x) * 8;
    if (i >= n) return;
    float4 a = *(const float4*)(in + i);
    float4 b = *(const float4*)(in + i + 4);
    u16 r[8] = {f2bf(a.x), f2bf(a.y), f2bf(a.z), f2bf(a.w),
                f2bf(b.x), f2bf(b.y), f2bf(b.z), f2bf(b.w)};
    *(uint4*)(out + i) = *(uint4*)r;
}

// ---------------- fp32 W (R x C) -> bf16 Wt (C x R), 64x64 tiles; z selects source ----------------
__global__ __launch_bounds__(256) void tcvt3_k(const float* __restrict__ in0, const float* __restrict__ in1,
                                               const float* __restrict__ in2, u16* __restrict__ out,
                                               int R, int C) {
    __shared__ u16 tile[64][68];
    const float* in = (blockIdx.z == 0) ? in0 : (blockIdx.z == 1) ? in1 : in2;
    u16* o = out + (size_t)blockIdx.z * R * C;
    int bx = blockIdx.x * 64, by = blockIdx.y * 64;
    int t = threadIdx.x;
    int r = t >> 4, c4 = (t & 15) * 4;
    #pragma unroll
    for (int i = 0; i < 4; ++i) {
        int row = by + r + i * 16;
        float4 v = *(const float4*)(in + (size_t)row * C + bx + c4);
        u16* d = &tile[r + i * 16][c4];
        d[0] = f2bf(v.x); d[1] = f2bf(v.y); d[2] = f2bf(v.z); d[3] = f2bf(v.w);
    }
    __syncthreads();
    int oc = t >> 4, r4 = (t & 15) * 4;
    #pragma unroll
    for (int i = 0; i < 4; ++i) {
        int orow = oc + i * 16;
        u16 v[4] = {tile[r4][orow], tile[r4 + 1][orow], tile[r4 + 2][orow], tile[r4 + 3][orow]};
        *(uint2*)&o[(size_t)(bx + orow) * R + by + r4] = *(const uint2*)v;
    }
}

// ---------------- legacy 128x128 MFMA GEMM (kept for MODE 2 = output projection) ----
template <int MODE>
__global__ __launch_bounds__(256) void gemm_bt(const u16* __restrict__ A, const u16* __restrict__ Bt,
                                               float* __restrict__ C2, u16* __restrict__ Oq,
                                               u16* __restrict__ Ok, u16* __restrict__ Ov,
                                               const float* __restrict__ ctab,
                                               const float* __restrict__ stab,
                                               int M, int N, int K) {
    __shared__ u16 SM[(MODE == 1) ? 16640 : 8192];
    u16* As = SM;
    u16* Bs = SM + 4096;
    int m0 = blockIdx.y * 128, n0 = blockIdx.x * 128;
    int t = threadIdx.x;
    int wid = t >> 6, lane = t & 63;
    int wr = wid >> 1, wc = wid & 1;
    f32x4v acc[4][4] = {};

    int c0 = wid * 128 + lane;
    int c1 = wid * 128 + 64 + lane;
    const u16* Ar0 = A + (size_t)(m0 + (c0 >> 2)) * K + (((c0 & 3) ^ ((c0 >> 3) & 3)) * 8);
    const u16* Ar1 = A + (size_t)(m0 + (c1 >> 2)) * K + (((c1 & 3) ^ ((c1 >> 3) & 3)) * 8);
    const u16* Br0 = Bt + (size_t)(n0 + (c0 >> 2)) * K + (((c0 & 3) ^ ((c0 >> 3) & 3)) * 8);
    const u16* Br1 = Bt + (size_t)(n0 + (c1 >> 2)) * K + (((c1 & 3) ^ ((c1 >> 3) & 3)) * 8);
    u16* Al0 = As + (size_t)(wid * 128) * 8;
    u16* Al1 = As + (size_t)(wid * 128 + 64) * 8;
    u16* Bl0 = Bs + (size_t)(wid * 128) * 8;
    u16* Bl1 = Bs + (size_t)(wid * 128 + 64) * 8;

    int sw = (lane >> 1) & 3;
    const u16* ap = As + (wr * 64 + (lane & 15)) * 32 + ((((lane >> 4)) ^ sw) << 3);
    const u16* bp = Bs + (wc * 64 + (lane & 15)) * 32 + ((((lane >> 4)) ^ sw) << 3);

    for (int kk = 0; kk < K; kk += 32) {
        gll16(Ar0 + kk, Al0);
        gll16(Ar1 + kk, Al1);
        gll16(Br0 + kk, Bl0);
        gll16(Br1 + kk, Bl1);
        __syncthreads();
        short8 a[4], b[4];
        #pragma unroll
        for (int i = 0; i < 4; ++i) {
            a[i] = *(const short8*)(ap + i * 512);
            b[i] = *(const short8*)(bp + i * 512);
        }
        #pragma unroll
        for (int mf = 0; mf < 4; ++mf)
            #pragma unroll
            for (int nf = 0; nf < 4; ++nf)
                acc[mf][nf] = __builtin_amdgcn_mfma_f32_16x16x32_bf16(a[mf], b[nf], acc[mf][nf], 0, 0, 0);
        __syncthreads();
    }

    int ln = lane & 15, lq = lane >> 4;
    if (MODE == 2) {
        int rb = m0 + wr * 64 + (lq << 2);
        int cb = n0 + wc * 64 + ln;
        #pragma unroll
        for (int mf = 0; mf < 4; ++mf)
            #pragma unroll
            for (int nf = 0; nf < 4; ++nf)
                #pragma unroll
                for (int r = 0; r < 4; ++r)
                    C2[(size_t)(rb + mf * 16 + r) * N + cb + nf * 16] = acc[mf][nf][r];
        return;
    }

    // MODE 1 epilogue (unused in this launch config, kept for completeness)
    u16* Es = SM;
    {
        int rl0 = wr * 64 + (lq << 2), cl0 = wc * 64 + ln;
        #pragma unroll
        for (int mf = 0; mf < 4; ++mf)
            #pragma unroll
            for (int nf = 0; nf < 4; ++nf)
                #pragma unroll
                for (int r = 0; r < 4; ++r)
                    Es[(rl0 + mf * 16 + r) * 130 + cl0 + nf * 16] = f2bf(acc[mf][nf][r]);
    }
    __syncthreads();

    int which = n0 >> 11;
    int h = (n0 & 2047) >> 7;
    int b_ = m0 >> 11;
    int s0 = m0 & (Sc - 1);

    if (which < 2) {
        u16* dst0 = which ? Ok : Oq;
        int r = t >> 1, h2 = t & 1;
        int s = s0 + r;
        const u16* row = Es + r * 130;
        const float* ct = ctab + (size_t)s * 64;
        const float* st = stab + (size_t)s * 64;
        u16* dp = dst0 + (((size_t)(b_ * Hc + h)) * Sc + s) * HDc + h2 * 64;
        #pragma unroll
        for (int j8 = 0; j8 < 64; j8 += 8) {
            uint4 aa = *(const uint4*)(row + j8);
            uint4 bb = *(const uint4*)(row + 64 + j8);
            const u16* ap8 = (const u16*)&aa;
            const u16* bp8 = (const u16*)&bb;
            float4 c0f = *(const float4*)(ct + j8);
            float4 c1f = *(const float4*)(ct + j8 + 4);
            float4 sn0 = *(const float4*)(st + j8);
            float4 sn1 = *(const float4*)(st + j8 + 4);
            float cc[8] = {c0f.x, c0f.y, c0f.z, c0f.w, c1f.x, c1f.y, c1f.z, c1f.w};
            float ss[8] = {sn0.x, sn0.y, sn0.z, sn0.w, sn1.x, sn1.y, sn1.z, sn1.w};
            u16 ov[8];
            #pragma unroll
            for (int e = 0; e < 8; ++e) {
                float x1 = bf2f(ap8[e]), x2 = bf2f(bp8[e]);
                ov[e] = h2 ? f2bf(x2 * cc[e] + x1 * ss[e]) : f2bf(x1 * cc[e] - x2 * ss[e]);
            }
            *(uint4*)(dp + j8) = *(const uint4*)ov;
        }
    } else {
        int d = t >> 1, sh = t & 1;
        u16* dp = Ov + (((size_t)(b_ * Hc + h)) * HDc + d) * Sc + s0 + sh * 64;
        #pragma unroll
        for (int r8 = 0; r8 < 64; r8 += 8) {
            u16 ov[8];
            #pragma unroll
            for (int e = 0; e < 8; ++e)
                ov[e] = Es[(sh * 64 + r8 + e) * 130 + d];
            *(uint4*)(dp + r8) = *(const uint4*)ov;
        }
    }
}

// ================= 256x256 BK=64 8-wave 8-phase GEMM (T1+T2+T3+T4+T5) =================
// A: M x K bf16 row-major (M=4096); Bt: N x K bf16 (N=6144 = [WqT;WkT;WvT]).
// Fused QKV epilogue: n<2048 -> Q (+RoPE), <4096 -> K (+RoPE), else V^T (B,H,HD,S).

#define FENCE asm volatile("" ::: "memory")

#define RDA(P, mh) do { _Pragma("unroll") for (int m_ = 0; m_ < 4; ++m_) { \
    aF[m_][0] = *(const short8*)((P) + (mh) * 4096 + m_ * 1024 + co0); \
    aF[m_][1] = *(const short8*)((P) + (mh) * 4096 + m_ * 1024 + co1); } } while (0)

#define RDB(P, nh) do { _Pragma("unroll") for (int n_ = 0; n_ < 2; ++n_) { \
    bF[(nh) * 2 + n_][0] = *(const short8*)((P) + ((nh) * 2 + n_) * 1024 + co0); \
    bF[(nh) * 2 + n_][1] = *(const short8*)((P) + ((nh) * 2 + n_) * 1024 + co1); } } while (0)

#define MFQ(mh, nh) do { _Pragma("unroll") for (int m_ = 0; m_ < 4; ++m_) { \
    _Pragma("unroll") for (int n_ = 0; n_ < 2; ++n_) { \
    f32x4v& c_ = acc[(mh) * 4 + m_][(nh) * 2 + n_]; \
    c_ = __builtin_amdgcn_mfma_f32_16x16x32_bf16(aF[m_][0], bF[(nh) * 2 + n_][0], c_, 0, 0, 0); \
    c_ = __builtin_amdgcn_mfma_f32_16x16x32_bf16(aF[m_][1], bF[(nh) * 2 + n_][1], c_, 0, 0, 0); } } } while (0)

#define PTAIL(mh, nh) do { FENCE; __builtin_amdgcn_s_barrier(); FENCE; \
    asm volatile("s_waitcnt lgkmcnt(0)" ::: "memory"); \
    __builtin_amdgcn_s_setprio(1); MFQ(mh, nh); __builtin_amdgcn_s_setprio(0); \
    FENCE; __builtin_amdgcn_s_barrier(); FENCE; } while (0)

__global__ __launch_bounds__(512, 2) void gemm256_qkv(
        const u16* __restrict__ A, const u16* __restrict__ Bt,
        u16* __restrict__ Oq, u16* __restrict__ Ok, u16* __restrict__ Ov,
        const float* __restrict__ ctab, const float* __restrict__ stab) {
    __shared__ u16 SM[65536]; // 128 KiB: As0|As1|Bs0|Bs1, each 256 rows x 64 cols bf16
    constexpr int K = Dc;     // 2048 -> 32 K-tiles of 64, 16 iterations x 2 K-tiles
    int t = threadIdx.x, wid = t >> 6, lane = t & 63;
    int wm = wid >> 2, wn = wid & 3;          // 2 x 4 wave grid; wave tile 128 x 64
    int ln = lane & 15, lq = lane >> 4;

    // XCD-aware bijective swizzle (nwg = 384, 384 % 8 == 0)
    int nx = gridDim.x;
    int lin = blockIdx.y * nx + blockIdx.x;
    int cpx = (nx * gridDim.y) >> 3;
    int swzb = (lin & 7) * cpx + (lin >> 3);
    int n0 = (swzb % nx) << 8;
    int m0 = (swzb / nx) << 8;

    u16* As0 = SM;
    u16* As1 = SM + 16384;
    u16* Bs0 = SM + 32768;
    u16* Bs1 = SM + 49152;

    // stage one 128-row half-tile (2 x gll16/thread). LDS is written LINEARLY by
    // global_load_lds; the read-side XOR swizzle (chunk ^= row&7) is applied by
    // permuting the GLOBAL source chunk (both-sides involution).
    auto stage = [&](const u16* G, int r0, int kt, u16* tile, int H) {
        #pragma unroll
        for (int L = 0; L < 2; ++L) {
            int ch16 = H * 1024 + L * 512 + wid * 64 + lane; // 16B-chunk index in tile
            int row = ch16 >> 3, ch = ch16 & 7;
            const u16* g = G + (size_t)(r0 + row) * K + kt * 64 + ((ch ^ (row & 7)) << 3);
            gll16(g, tile + (H * 1024 + L * 512 + wid * 64) * 8);
        }
    };

    // prologue: K-tile 0 complete (8 loads) + K-tile 1 H0 halves (4 loads)
    stage(Bt, n0, 0, Bs0, 0);
    stage(Bt, n0, 0, Bs0, 1);
    stage(A,  m0, 0, As0, 0);
    stage(A,  m0, 0, As0, 1);
    stage(Bt, n0, 1, Bs1, 0);
    stage(A,  m0, 1, As1, 0);

    const u16* aR0 = SM + (wm * 128 + ln) * 64;
    const u16* aR1 = aR0 + 16384;
    const u16* bR0 = SM + 32768 + (wn * 64 + ln) * 64;
    const u16* bR1 = bR0 + 16384;
    int sw = ln & 7;
    int co0 = (lq ^ sw) << 3;        // k-slice 0 chunk (swizzled), u16 units
    int co1 = ((4 | lq) ^ sw) << 3;  // k-slice 1 chunk

    short8 aF[4][2], bF[4][2];
    f32x4v acc[8][4] = {};

    asm volatile("s_waitcnt vmcnt(4)" ::: "memory"); // K-tile 0 resident
    FENCE; __builtin_amdgcn_s_barrier(); FENCE;

    for (int it = 0; it < K / 128; ++it) {
        int k1 = (2 * it + 1) & 31, k2 = (2 * it + 2) & 31, k3 = (2 * it + 3) & 31;
        // ---- K-tile 2it (buf0) ----
        // P1: A-low + B-low, stage kt1.B.H1
        RDA(aR0, 0); RDB(bR0, 0);
        stage(Bt, n0, k1, Bs1, 1);
        asm volatile("s_waitcnt lgkmcnt(8)" ::: "memory");
        PTAIL(0, 0);
        // P2: B-high, stage kt1.A.H1
        RDB(bR0, 1);
        stage(A, m0, k1, As1, 1);
        PTAIL(0, 1);
        // P3: A-high, stage kt2.B.H0 (buf0 B reads done at end of P2)
        RDA(aR0, 1);
        stage(Bt, n0, k2, Bs0, 0);
        PTAIL(1, 0);
        // P4: stage kt2.A.H0 (buf0 A reads done at end of P3); counted wait -> kt1 resident
        stage(A, m0, k2, As0, 0);
        asm volatile("s_waitcnt vmcnt(4)" ::: "memory");
        PTAIL(1, 1);
        // ---- K-tile 2it+1 (buf1) ----
        // P5
        RDA(aR1, 0); RDB(bR1, 0);
        stage(Bt, n0, k2, Bs0, 1);
        asm volatile("s_waitcnt lgkmcnt(8)" ::: "memory");
        PTAIL(0, 0);
        // P6
        RDB(bR1, 1);
        stage(A, m0, k2, As0, 1);
        PTAIL(0, 1);
        // P7
        RDA(aR1, 1);
        stage(Bt, n0, k3, Bs1, 0);
        PTAIL(1, 0);
        // P8: counted wait -> kt2 resident for next P1
        stage(A, m0, k3, As1, 0);
        asm volatile("s_waitcnt vmcnt(4)" ::: "memory");
        PTAIL(1, 1);
    }
    asm volatile("s_waitcnt vmcnt(0)" ::: "memory"); // drain before LDS reuse
    __syncthreads();

    // ---- epilogue: two 128-row halves through a 128 x 258 bf16 LDS strip ----
    int which = n0 >> 11;            // 0=Q,1=K,2=V
    int h0 = (n0 & 2047) >> 7;       // tile covers heads h0, h0+1
    int b_ = m0 >> 11;
    int s0 = m0 & (Sc - 1);
    u16* Es = SM;
    const int ESTR = 258;

    #pragma unroll
    for (int Hh = 0; Hh < 2; ++Hh) {
        if (wm == Hh) {
            #pragma unroll
            for (int mf = 0; mf < 8; ++mf)
                #pragma unroll
                for (int nf = 0; nf < 4; ++nf)
                    #pragma unroll
                    for (int r = 0; r < 4; ++r)
                        Es[(mf * 16 + (lq << 2) + r) * ESTR + wn * 64 + nf * 16 + ln] =
                            f2bf(acc[mf][nf][r]);
        }
        __syncthreads();
        if (which < 2) {
            u16* dst0 = which ? Ok : Oq;
            int u = t >> 1, h2 = t & 1;
            int r = u & 127, hh = u >> 7;
            int s = s0 + Hh * 128 + r;
            const u16* rowp = Es + r * ESTR + hh * 128;
            const float* ct = ctab + (size_t)s * 64;
            const float* st = stab + (size_t)s * 64;
            u16* dp = dst0 + (((size_t)(b_ * Hc + h0 + hh)) * Sc + s) * HDc + h2 * 64;
            #pragma unroll
            for (int j8 = 0; j8 < 64; j8 += 8) {
                uint4 aa = *(const uint4*)(rowp + j8);
                uint4 bb = *(const uint4*)(rowp + 64 + j8);
                const u16* ap8 = (const u16*)&aa;
                const u16* bp8 = (const u16*)&bb;
                float4 c0f = *(const float4*)(ct + j8);
                float4 c1f = *(const float4*)(ct + j8 + 4);
                float4 sn0 = *(const float4*)(st + j8);
                float4 sn1 = *(const float4*)(st + j8 + 4);
                float cc[8] = {c0f.x, c0f.y, c0f.z, c0f.w, c1f.x, c1f.y, c1f.z, c1f.w};
                float ss[8] = {sn0.x, sn0.y, sn0.z, sn0.w, sn1.x, sn1.y, sn1.z, sn1.w};
                u16 ov[8];
                #pragma unroll
                for (int e = 0; e < 8; ++e) {
                    float x1 = bf2f(ap8[e]), x2 = bf2f(bp8[e]);
                    ov[e] = h2 ? f2bf(x2 * cc[e] + x1 * ss[e]) : f2bf(x1 * cc[e] - x2 * ss[e]);
                }
                *(uint4*)(dp + j8) = *(const uint4*)ov;
            }
        } else {
            int u = t >> 1, sh = t & 1;
            int d = u & 127, hh = u >> 7;
            u16* dp = Ov + (((size_t)(b_ * Hc + h0 + hh)) * HDc + d) * Sc + s0 + Hh * 128 + sh * 64;
            #pragma unroll
            for (int r8 = 0; r8 < 64; r8 += 8) {
                u16 ov[8];
                #pragma unroll
                for (int e = 0; e < 8; ++e)
                    ov[e] = Es[(sh * 64 + r8 + e) * ESTR + hh * 128 + d];
                *(uint4*)(dp + r8) = *(const uint4*)ov;
            }
        }
        __syncthreads();
    }
}

// ---------------- MFMA flash attention, fixed-shift softmax, swizzled LDS ----------------
__global__ __launch_bounds__(256) void fattn_k(const u16* __restrict__ Q, const u16* __restrict__ K,
                                               const u16* __restrict__ Vt, u16* __restrict__ ctx) {
    __shared__ u16 KsA[8192];
    __shared__ u16 VsA[8192];
    __shared__ u16 PsA[4 * 32 * 72];
    int t = threadIdx.x, wid = t >> 6, lane = t & 63;
    int bh = blockIdx.x;
    int yt = blockIdx.y;
    int qi = (yt < 8) ? yt : 23 - yt;
    int q0 = qi << 7;
    int wrow0 = q0 + wid * 32;
    const u16* Qb = Q + ((size_t)bh * Sc + wrow0) * HDc;
    const u16* Kb = K + (size_t)bh * Sc * HDc;
    const u16* Vb = Vt + (size_t)bh * HDc * Sc;
    int ln = lane & 15, lq = lane >> 4;
    u16* psw = PsA + wid * 32 * 72;

    short8 aq[2][4];
    #pragma unroll
    for (int mf = 0; mf < 2; ++mf)
        #pragma unroll
        for (int ks = 0; ks < 4; ++ks)
            aq[mf][ks] = *(const short8*)(Qb + (size_t)(mf * 16 + ln) * HDc + ks * 32 + lq * 8);

    short8 onesb;
    {
        short v = (ln == 0) ? (short)0x3F80 : (short)0;
        #pragma unroll
        for (int e = 0; e < 8; ++e) onesb[e] = v;
    }

    f32x4v o[2][8] = {};
    f32x4v lacc[2] = {};

    const float sc = 0.08838834764831845f;
    const float SHIFT = 12.0f;
    int jendw = wrow0 + 31;
    int jendb = q0 + 127;
    int swz = (ln >> 1) & 3;

    for (int j0 = 0; j0 <= jendb; j0 += 64) {
        #pragma unroll
        for (int i = 0; i < 4; ++i) {
            int p = (wid * 4 + i) * 64 + lane;
            int plane = p >> 8, key = (p >> 2) & 63;
            int qc = (p & 3) ^ ((key >> 1) & 3);
            gll16(Kb + (size_t)(j0 + key) * HDc + plane * 32 + qc * 8,
                  KsA + (size_t)(wid * 4 + i) * 512);
        }
        #pragma unroll
        for (int i = 0; i < 4; ++i) {
            int p = (wid * 4 + i) * 64 + lane;
            int plane = p >> 9, d = (p >> 2) & 127;
            int qc = (p & 3) ^ ((d >> 1) & 3);
            gll16(Vb + (size_t)d * Sc + j0 + plane * 32 + qc * 8,
                  VsA + (size_t)(wid * 4 + i) * 512);
        }
        __syncthreads();

        if (j0 <= jendw) {
            f32x4v sf[2][4] = {};
            #pragma unroll
            for (int ks = 0; ks < 4; ++ks)
                #pragma unroll
                for (int nf = 0; nf < 4; ++nf) {
                    short8 bk = *(const short8*)(KsA + ks * 2048 + (nf * 16 + ln) * 32 + ((lq ^ swz) << 3));
                    sf[0][nf] = __builtin_amdgcn_mfma_f32_16x16x32_bf16(aq[0][ks], bk, sf[0][nf], 0, 0, 0);
                    sf[1][nf] = __builtin_amdgcn_mfma_f32_16x16x32_bf16(aq[1][ks], bk, sf[1][nf], 0, 0, 0);
                }

            bool diag = (j0 + 63 > wrow0);
            #pragma unroll
            for (int mf = 0; mf < 2; ++mf) {
                int rowb = mf * 16 + (lq << 2);
                #pragma unroll
                for (int nf = 0; nf < 4; ++nf) {
                    int col = nf * 16 + ln;
                    int ck = col >> 3, cl = col & 7;
                    #pragma unroll
                    for (int r = 0; r < 4; ++r) {
                        float p = __expf(fmaf(sf[mf][nf][r], sc, -SHIFT));
                        if (diag && (j0 + col > wrow0 + rowb + r)) p = 0.f;
                        int row = rowb + r;
                        psw[row * 72 + ((ck ^ (row & 7)) << 3) + cl] = f2bf(p);
                    }
                }
            }

            short8 ap0[2][2];
            #pragma unroll
            for (int mf = 0; mf < 2; ++mf)
                #pragma unroll
                for (int ks = 0; ks < 2; ++ks)
                    ap0[mf][ks] = *(const short8*)(psw + (mf * 16 + ln) * 72 + (((ks * 4 + lq) ^ (ln & 7)) << 3));
            #pragma unroll
            for (int ks = 0; ks < 2; ++ks) {
                lacc[0] = __builtin_amdgcn_mfma_f32_16x16x32_bf16(ap0[0][ks], onesb, lacc[0], 0, 0, 0);
                lacc[1] = __builtin_amdgcn_mfma_f32_16x16x32_bf16(ap0[1][ks], onesb, lacc[1], 0, 0, 0);
                #pragma unroll
                for (int nd = 0; nd < 8; ++nd) {
                    short8 bv = *(const short8*)(VsA + ks * 4096 + (nd * 16 + ln) * 32 + ((lq ^ swz) << 3));
                    o[0][nd] = __builtin_amdgcn_mfma_f32_16x16x32_bf16(ap0[0][ks], bv, o[0][nd], 0, 0, 0);
                    o[1][nd] = __builtin_amdgcn_mfma_f32_16x16x32_bf16(ap0[1][ks], bv, o[1][nd], 0, 0, 0);
                }
            }
        }
        __syncthreads();
    }

    int b = bh >> 4, h = bh & 15;
    #pragma unroll
    for (int mf = 0; mf < 2; ++mf)
        #pragma unroll
        for (int r = 0; r < 4; ++r) {
            float lv = __shfl(lacc[mf][r], lane & 48, 64);
            float inv = 1.0f / lv;
            int q = wrow0 + mf * 16 + (lq << 2) + r;
            u16* cp = ctx + (((size_t)(b * Sc + q)) * Hc + h) * HDc + ln;
            #pragma unroll
            for (int nd = 0; nd < 8; ++nd)
                cp[nd * 16] = f2bf(o[mf][nd][r] * inv);
        }
}

extern "C" void kernel_launch(void* const* d_in, const int* in_sizes, int n_in,
                              void* d_out, int out_size, void* d_ws, size_t ws_size,
                              hipStream_t stream) {
    (void)in_sizes; (void)n_in; (void)out_size; (void)ws_size;
    const float* x  = (const float*)d_in[0];
    const float* Wq = (const float*)d_in[2];
    const float* Wk = (const float*)d_in[3];
    const float* Wv = (const float*)d_in[4];
    const float* Wo = (const float*)d_in[5];

    char* w = (char*)d_ws;
    u16* Wt  = (u16*)w; w += (size_t)3 * Dc * Dc * 2;
    u16* Qb  = (u16*)w; w += (size_t)Bc * Hc * Sc * HDc * 2;
    u16* Kb  = (u16*)w; w += (size_t)Bc * Hc * Sc * HDc * 2;
    u16* Vb  = (u16*)w; w += (size_t)Bc * Hc * Sc * HDc * 2;
    u16* ctx = (u16*)w; w += (size_t)Bc * Sc * Hc * HDc * 2;
    float* ctab = (float*)w; w += (size_t)Sc * 64 * 4;
    float* stab = (float*)w; w += (size_t)Sc * 64 * 4;
    u16* xb = (u16*)d_out;

    rope_tab_k<<<dim3(Sc * 64 / 256), 256, 0, stream>>>(ctab, stab);

    int nx = Bc * Sc * Dc;
    cvt_k<<<dim3(nx / 2048), 256, 0, stream>>>(x, xb, nx);

    tcvt3_k<<<dim3(Dc / 64, Dc / 64, 3), 256, 0, stream>>>(Wq, Wk, Wv, Wt, Dc, Dc);
    gemm256_qkv<<<dim3(3 * Dc / 256, (Bc * Sc) / 256), 512, 0, stream>>>(
        xb, Wt, Qb, Kb, Vb, ctab, stab);

    fattn_k<<<dim3(Bc * Hc, Sc / 128), 256, 0, stream>>>(Qb, Kb, Vb, ctx);

    tcvt3_k<<<dim3(Dc / 64, Dc / 64, 1), 256, 0, stream>>>(Wo, Wo, Wo, Wt, Dc, Dc);
    gemm_bt<2><<<dim3(Dc / 128, (Bc * Sc) / 128), 256, 0, stream>>>(
        ctx, Wt, (float*)d_out, nullptr, nullptr, nullptr, nullptr, nullptr, Bc * Sc, Dc, Dc);
}

// Round 2
// 424.166 us; speedup vs baseline: 1.0384x; 1.0003x over previous
//
#include <hip/hip_runtime.h>

typedef unsigned short u16;
typedef unsigned int u32;

constexpr int Bc = 2, Sc = 2048, Dc = 2048, Hc = 16, HDc = 128;

using short8 = __attribute__((ext_vector_type(8))) short;
using f32x4v = __attribute__((ext_vector_type(4))) float;

static __device__ __forceinline__ float bf2f(u16 v) { return __uint_as_float(((u32)v) << 16); }
static __device__ __forceinline__ u16 f2bf(float f) {
    u32 u = __float_as_uint(f);
    return (u16)((u + 0x7fffu + ((u >> 16) & 1u)) >> 16);
}

// async global->LDS, 16B per lane; LDS dest = wave-uniform base + lane*16
__device__ __forceinline__ void gll16(const u16* g, u16* l) {
    __builtin_amdgcn_global_load_lds((const __attribute__((address_space(1))) void*)g,
                                     (__attribute__((address_space(3))) void*)l, 16, 0, 0);
}

// ---------------- RoPE cos/sin tables: [S][64] fp32 ----------------
__global__ __launch_bounds__(256) void rope_tab_k(float* __restrict__ ctab, float* __restrict__ stab) {
    int idx = blockIdx.x * 256 + threadIdx.x; // S*64 threads
    int s = idx >> 6, i = idx & 63;
    float freq = exp2f(-(float)i * 0.20762050593045952f); // 10000^(-i/64)
    float ang = (float)s * freq;
    float c, sn;
    sincosf(ang, &sn, &c);
    ctab[idx] = c;
    stab[idx] = sn;
}

// ---------------- fp32 -> bf16 bulk convert ----------------
__global__ __launch_bounds__(256) void cvt_k(const float* __restrict__ in, u16* __restrict__ out, int n) {
    int i = (blockIdx.x * 256 + threadIdx.x) * 8;
    if (i >= n) return;
    float4 a = *(const float4*)(in + i);
    float4 b = *(const float4*)(in + i + 4);
    u16 r[8] = {f2bf(a.x), f2bf(a.y), f2bf(a.z), f2bf(a.w),
                f2bf(b.x), f2bf(b.y), f2bf(b.z), f2bf(b.w)};
    *(uint4*)(out + i) = *(uint4*)r;
}

// ---------------- fp32 W (R x C) -> bf16 Wt (C x R), 64x64 tiles; z selects source ----------------
__global__ __launch_bounds__(256) void tcvt3_k(const float* __restrict__ in0, const float* __restrict__ in1,
                                               const float* __restrict__ in2, u16* __restrict__ out,
                                               int R, int C) {
    __shared__ u16 tile[64][68];
    const float* in = (blockIdx.z == 0) ? in0 : (blockIdx.z == 1) ? in1 : in2;
    u16* o = out + (size_t)blockIdx.z * R * C;
    int bx = blockIdx.x * 64, by = blockIdx.y * 64;
    int t = threadIdx.x;
    int r = t >> 4, c4 = (t & 15) * 4;
    #pragma unroll
    for (int i = 0; i < 4; ++i) {
        int row = by + r + i * 16;
        float4 v = *(const float4*)(in + (size_t)row * C + bx + c4);
        u16* d = &tile[r + i * 16][c4];
        d[0] = f2bf(v.x); d[1] = f2bf(v.y); d[2] = f2bf(v.z); d[3] = f2bf(v.w);
    }
    __syncthreads();
    int oc = t >> 4, r4 = (t & 15) * 4;
    #pragma unroll
    for (int i = 0; i < 4; ++i) {
        int orow = oc + i * 16;
        u16 v[4] = {tile[r4][orow], tile[r4 + 1][orow], tile[r4 + 2][orow], tile[r4 + 3][orow]};
        *(uint2*)&o[(size_t)(bx + orow) * R + by + r4] = *(const uint2*)v;
    }
}

// ---------------- legacy 128x128 MFMA GEMM (MODE 2 = output projection) ----
template <int MODE>
__global__ __launch_bounds__(256) void gemm_bt(const u16* __restrict__ A, const u16* __restrict__ Bt,
                                               float* __restrict__ C2,
                                               int M, int N, int K) {
    __shared__ u16 SM[8192];
    u16* As = SM;
    u16* Bs = SM + 4096;
    int m0 = blockIdx.y * 128, n0 = blockIdx.x * 128;
    int t = threadIdx.x;
    int wid = t >> 6, lane = t & 63;
    int wr = wid >> 1, wc = wid & 1;
    f32x4v acc[4][4] = {};

    int c0 = wid * 128 + lane;
    int c1 = wid * 128 + 64 + lane;
    const u16* Ar0 = A + (size_t)(m0 + (c0 >> 2)) * K + (((c0 & 3) ^ ((c0 >> 3) & 3)) * 8);
    const u16* Ar1 = A + (size_t)(m0 + (c1 >> 2)) * K + (((c1 & 3) ^ ((c1 >> 3) & 3)) * 8);
    const u16* Br0 = Bt + (size_t)(n0 + (c0 >> 2)) * K + (((c0 & 3) ^ ((c0 >> 3) & 3)) * 8);
    const u16* Br1 = Bt + (size_t)(n0 + (c1 >> 2)) * K + (((c1 & 3) ^ ((c1 >> 3) & 3)) * 8);
    u16* Al0 = As + (size_t)(wid * 128) * 8;
    u16* Al1 = As + (size_t)(wid * 128 + 64) * 8;
    u16* Bl0 = Bs + (size_t)(wid * 128) * 8;
    u16* Bl1 = Bs + (size_t)(wid * 128 + 64) * 8;

    int sw = (lane >> 1) & 3;
    const u16* ap = As + (wr * 64 + (lane & 15)) * 32 + ((((lane >> 4)) ^ sw) << 3);
    const u16* bp = Bs + (wc * 64 + (lane & 15)) * 32 + ((((lane >> 4)) ^ sw) << 3);

    for (int kk = 0; kk < K; kk += 32) {
        gll16(Ar0 + kk, Al0);
        gll16(Ar1 + kk, Al1);
        gll16(Br0 + kk, Bl0);
        gll16(Br1 + kk, Bl1);
        __syncthreads();
        short8 a[4], b[4];
        #pragma unroll
        for (int i = 0; i < 4; ++i) {
            a[i] = *(const short8*)(ap + i * 512);
            b[i] = *(const short8*)(bp + i * 512);
        }
        #pragma unroll
        for (int mf = 0; mf < 4; ++mf)
            #pragma unroll
            for (int nf = 0; nf < 4; ++nf)
                acc[mf][nf] = __builtin_amdgcn_mfma_f32_16x16x32_bf16(a[mf], b[nf], acc[mf][nf], 0, 0, 0);
        __syncthreads();
    }

    int ln = lane & 15, lq = lane >> 4;
    int rb = m0 + wr * 64 + (lq << 2);
    int cb = n0 + wc * 64 + ln;
    #pragma unroll
    for (int mf = 0; mf < 4; ++mf)
        #pragma unroll
        for (int nf = 0; nf < 4; ++nf)
            #pragma unroll
            for (int r = 0; r < 4; ++r)
                C2[(size_t)(rb + mf * 16 + r) * N + cb + nf * 16] = acc[mf][nf][r];
}

// ================= 128x256 BK=64 8-wave triple-buffer GEMM (T1+T2+T3+T4+T5) =========
// A: M x K bf16 row-major (M=4096); Bt: N x K bf16 (N=6144 = [WqT;WkT;WvT]).
// 768 blocks = exactly 3 rounds of 256 CUs. 2 phases per K-tile, 16 MFMA each.
// Fused QKV epilogue: n<2048 -> Q (+RoPE), <4096 -> K (+RoPE), else V^T (B,H,HD,S).

#define FENCE asm volatile("" ::: "memory")

#define RDA8(P) do { _Pragma("unroll") for (int m_ = 0; m_ < 4; ++m_) { \
    aF[m_][0] = *(const short8*)((P) + m_ * 1024 + co0); \
    aF[m_][1] = *(const short8*)((P) + m_ * 1024 + co1); } } while (0)

#define RDB2(P, nh) do { _Pragma("unroll") for (int j_ = 0; j_ < 2; ++j_) { \
    bF[j_][0] = *(const short8*)((P) + ((nh) * 2 + j_) * 1024 + co0); \
    bF[j_][1] = *(const short8*)((P) + ((nh) * 2 + j_) * 1024 + co1); } } while (0)

#define MFQ8(nh) do { _Pragma("unroll") for (int m_ = 0; m_ < 4; ++m_) \
    _Pragma("unroll") for (int j_ = 0; j_ < 2; ++j_) { \
    f32x4v& c_ = acc[m_][(nh) * 2 + j_]; \
    c_ = __builtin_amdgcn_mfma_f32_16x16x32_bf16(aF[m_][0], bF[j_][0], c_, 0, 0, 0); \
    c_ = __builtin_amdgcn_mfma_f32_16x16x32_bf16(aF[m_][1], bF[j_][1], c_, 0, 0, 0); } } while (0)

#define PT(nh) do { FENCE; __builtin_amdgcn_s_barrier(); FENCE; \
    asm volatile("s_waitcnt lgkmcnt(0)" ::: "memory"); \
    __builtin_amdgcn_s_setprio(1); MFQ8(nh); __builtin_amdgcn_s_setprio(0); \
    FENCE; __builtin_amdgcn_s_barrier(); FENCE; } while (0)

// KST >= 0: stage K-tile KST (A into ADST, B into BDST). VW: vmcnt wait at phase 1.
#define KTILE(aRb, bRb, KST, ADST, BDST, VW) do { \
    RDA8(aRb); RDB2(bRb, 0); \
    if ((KST) >= 0) stageA(KST, ADST); \
    PT(0); \
    RDB2(bRb, 1); \
    if ((KST) >= 0) stageB(KST, BDST); \
    if ((VW) == 6) asm volatile("s_waitcnt vmcnt(6)" ::: "memory"); \
    else if ((VW) == 0) asm volatile("s_waitcnt vmcnt(0)" ::: "memory"); \
    PT(1); } while (0)

__global__ __launch_bounds__(512, 2) void gemm128_qkv(
        const u16* __restrict__ A, const u16* __restrict__ Bt,
        u16* __restrict__ Oq, u16* __restrict__ Ok, u16* __restrict__ Ov,
        const float* __restrict__ ctab, const float* __restrict__ stab) {
    __shared__ u16 SM[73728]; // 144 KiB: A x3 (16KB each) + B x3 (32KB each)
    constexpr int K = Dc;     // 2048 -> 32 K-tiles of 64
    constexpr int NT = 32;
    int t = threadIdx.x, wid = t >> 6, lane = t & 63;
    int wm = wid >> 2, wn = wid & 3;          // 2 x 4 wave grid; wave tile 64 x 64
    int ln = lane & 15, lq = lane >> 4;

    // XCD-aware bijective swizzle (nwg = 768, 768 % 8 == 0)
    int nx = gridDim.x; // 24
    int lin = blockIdx.y * nx + blockIdx.x;
    int cpx = (nx * gridDim.y) >> 3; // 96
    int swzb = (lin & 7) * cpx + (lin >> 3);
    int n0 = (swzb % nx) << 8;
    int m0 = (swzb / nx) << 7;

    u16* As0 = SM;
    u16* As1 = SM + 8192;
    u16* As2 = SM + 16384;
    u16* Bs0 = SM + 24576;
    u16* Bs1 = SM + 40960;
    u16* Bs2 = SM + 57344;

    // stage K-tile: LDS written LINEARLY by global_load_lds; read-side XOR swizzle
    // (chunk ^= row&7) realized by permuting the GLOBAL source chunk (involution).
    auto stageA = [&](int kt, u16* dst) {
        #pragma unroll
        for (int L = 0; L < 2; ++L) {
            int ch16 = L * 512 + wid * 64 + lane; // 16B-chunk index, 128x64 tile
            int row = ch16 >> 3, ch = ch16 & 7;
            gll16(A + (size_t)(m0 + row) * K + kt * 64 + ((ch ^ (row & 7)) << 3),
                  dst + (L * 512 + wid * 64) * 8);
        }
    };
    auto stageB = [&](int kt, u16* dst) {
        #pragma unroll
        for (int L = 0; L < 4; ++L) {
            int ch16 = L * 512 + wid * 64 + lane; // 16B-chunk index, 256x64 tile
            int row = ch16 >> 3, ch = ch16 & 7;
            gll16(Bt + (size_t)(n0 + row) * K + kt * 64 + ((ch ^ (row & 7)) << 3),
                  dst + (L * 512 + wid * 64) * 8);
        }
    };

    const u16* aR0 = As0 + (wm * 64 + ln) * 64;
    const u16* aR1 = As1 + (wm * 64 + ln) * 64;
    const u16* aR2 = As2 + (wm * 64 + ln) * 64;
    const u16* bR0 = Bs0 + (wn * 64 + ln) * 64;
    const u16* bR1 = Bs1 + (wn * 64 + ln) * 64;
    const u16* bR2 = Bs2 + (wn * 64 + ln) * 64;
    int sw = ln & 7;
    int co0 = (lq ^ sw) << 3;        // k-slice 0 chunk (swizzled), u16 units
    int co1 = ((4 | lq) ^ sw) << 3;  // k-slice 1 chunk

    short8 aF[4][2], bF[2][2];
    f32x4v acc[4][4] = {};

    // prologue: K-tiles 0 and 1 (6 loads each, in order)
    stageA(0, As0); stageB(0, Bs0);
    stageA(1, As1); stageB(1, Bs1);
    asm volatile("s_waitcnt vmcnt(6)" ::: "memory"); // kt0 resident, kt1 in flight
    FENCE; __builtin_amdgcn_s_barrier(); FENCE;

    // main loop: kt = 0..29 (stage kt+2), then 2 tail K-tiles
    for (int k3 = 0; k3 < NT - 2; k3 += 3) {
        KTILE(aR0, bR0, k3 + 2, As2, Bs2, 6);
        KTILE(aR1, bR1, k3 + 3, As0, Bs0, 6);
        KTILE(aR2, bR2, k3 + 4, As1, Bs1, 6);
    }
    KTILE(aR0, bR0, -1, As0, Bs0, 0);  // kt=30; drain so kt31 resident
    KTILE(aR1, bR1, -1, As0, Bs0, -1); // kt=31

    asm volatile("s_waitcnt vmcnt(0)" ::: "memory"); // drain before LDS reuse
    __syncthreads();

    // ---- epilogue: 128 x 258 bf16 LDS strip, then coalesced fused writes ----
    int which = n0 >> 11;            // 0=Q,1=K,2=V
    int h0 = (n0 & 2047) >> 7;       // tile covers heads h0, h0+1
    int b_ = m0 >> 11;
    int s0 = m0 & (Sc - 1);
    u16* Es = SM;
    const int ESTR = 258;

    #pragma unroll
    for (int mf = 0; mf < 4; ++mf)
        #pragma unroll
        for (int nf = 0; nf < 4; ++nf)
            #pragma unroll
            for (int r = 0; r < 4; ++r)
                Es[(wm * 64 + mf * 16 + (lq << 2) + r) * ESTR + wn * 64 + nf * 16 + ln] =
                    f2bf(acc[mf][nf][r]);
    __syncthreads();

    if (which < 2) {
        // Q or K: +RoPE. thread t: (head-half hh, row r) from t>>1, half h2=t&1.
        u16* dst0 = which ? Ok : Oq;
        int u = t >> 1, h2 = t & 1;
        int r = u & 127, hh = u >> 7;
        int s = s0 + r;
        const u16* rowp = Es + r * ESTR + hh * 128;
        const float* ct = ctab + (size_t)s * 64;
        const float* st = stab + (size_t)s * 64;
        u16* dp = dst0 + (((size_t)(b_ * Hc + h0 + hh)) * Sc + s) * HDc + h2 * 64;
        #pragma unroll
        for (int j8 = 0; j8 < 64; j8 += 8) {
            uint4 aa = *(const uint4*)(rowp + j8);
            uint4 bb = *(const uint4*)(rowp + 64 + j8);
            const u16* ap8 = (const u16*)&aa;
            const u16* bp8 = (const u16*)&bb;
            float4 c0f = *(const float4*)(ct + j8);
            float4 c1f = *(const float4*)(ct + j8 + 4);
            float4 sn0 = *(const float4*)(st + j8);
            float4 sn1 = *(const float4*)(st + j8 + 4);
            float cc[8] = {c0f.x, c0f.y, c0f.z, c0f.w, c1f.x, c1f.y, c1f.z, c1f.w};
            float ss[8] = {sn0.x, sn0.y, sn0.z, sn0.w, sn1.x, sn1.y, sn1.z, sn1.w};
            u16 ov[8];
            #pragma unroll
            for (int e = 0; e < 8; ++e) {
                float x1 = bf2f(ap8[e]), x2 = bf2f(bp8[e]);
                ov[e] = h2 ? f2bf(x2 * cc[e] + x1 * ss[e]) : f2bf(x1 * cc[e] - x2 * ss[e]);
            }
            *(uint4*)(dp + j8) = *(const uint4*)ov;
        }
    } else {
        // V^T: thread t: (head-half hh, col d) from t>>1, s-half sh=t&1.
        int u = t >> 1, sh = t & 1;
        int d = u & 127, hh = u >> 7;
        u16* dp = Ov + (((size_t)(b_ * Hc + h0 + hh)) * HDc + d) * Sc + s0 + sh * 64;
        #pragma unroll
        for (int r8 = 0; r8 < 64; r8 += 8) {
            u16 ov[8];
            #pragma unroll
            for (int e = 0; e < 8; ++e)
                ov[e] = Es[(sh * 64 + r8 + e) * ESTR + hh * 128 + d];
            *(uint4*)(dp + r8) = *(const uint4*)ov;
        }
    }
}

// ---------------- MFMA flash attention, fixed-shift softmax, swizzled LDS ----------------
__global__ __launch_bounds__(256) void fattn_k(const u16* __restrict__ Q, const u16* __restrict__ K,
                                               const u16* __restrict__ Vt, u16* __restrict__ ctx) {
    __shared__ u16 KsA[8192];
    __shared__ u16 VsA[8192];
    __shared__ u16 PsA[4 * 32 * 72];
    int t = threadIdx.x, wid = t >> 6, lane = t & 63;
    int bh = blockIdx.x;
    int yt = blockIdx.y;
    int qi = (yt < 8) ? yt : 23 - yt;
    int q0 = qi << 7;
    int wrow0 = q0 + wid * 32;
    const u16* Qb = Q + ((size_t)bh * Sc + wrow0) * HDc;
    const u16* Kb = K + (size_t)bh * Sc * HDc;
    const u16* Vb = Vt + (size_t)bh * HDc * Sc;
    int ln = lane & 15, lq = lane >> 4;
    u16* psw = PsA + wid * 32 * 72;

    short8 aq[2][4];
    #pragma unroll
    for (int mf = 0; mf < 2; ++mf)
        #pragma unroll
        for (int ks = 0; ks < 4; ++ks)
            aq[mf][ks] = *(const short8*)(Qb + (size_t)(mf * 16 + ln) * HDc + ks * 32 + lq * 8);

    short8 onesb;
    {
        short v = (ln == 0) ? (short)0x3F80 : (short)0;
        #pragma unroll
        for (int e = 0; e < 8; ++e) onesb[e] = v;
    }

    f32x4v o[2][8] = {};
    f32x4v lacc[2] = {};

    const float sc = 0.08838834764831845f;
    const float SHIFT = 12.0f;
    int jendw = wrow0 + 31;
    int jendb = q0 + 127;
    int swz = (ln >> 1) & 3;

    for (int j0 = 0; j0 <= jendb; j0 += 64) {
        #pragma unroll
        for (int i = 0; i < 4; ++i) {
            int p = (wid * 4 + i) * 64 + lane;
            int plane = p >> 8, key = (p >> 2) & 63;
            int qc = (p & 3) ^ ((key >> 1) & 3);
            gll16(Kb + (size_t)(j0 + key) * HDc + plane * 32 + qc * 8,
                  KsA + (size_t)(wid * 4 + i) * 512);
        }
        #pragma unroll
        for (int i = 0; i < 4; ++i) {
            int p = (wid * 4 + i) * 64 + lane;
            int plane = p >> 9, d = (p >> 2) & 127;
            int qc = (p & 3) ^ ((d >> 1) & 3);
            gll16(Vb + (size_t)d * Sc + j0 + plane * 32 + qc * 8,
                  VsA + (size_t)(wid * 4 + i) * 512);
        }
        __syncthreads();

        if (j0 <= jendw) {
            f32x4v sf[2][4] = {};
            #pragma unroll
            for (int ks = 0; ks < 4; ++ks)
                #pragma unroll
                for (int nf = 0; nf < 4; ++nf) {
                    short8 bk = *(const short8*)(KsA + ks * 2048 + (nf * 16 + ln) * 32 + ((lq ^ swz) << 3));
                    sf[0][nf] = __builtin_amdgcn_mfma_f32_16x16x32_bf16(aq[0][ks], bk, sf[0][nf], 0, 0, 0);
                    sf[1][nf] = __builtin_amdgcn_mfma_f32_16x16x32_bf16(aq[1][ks], bk, sf[1][nf], 0, 0, 0);
                }

            bool diag = (j0 + 63 > wrow0);
            #pragma unroll
            for (int mf = 0; mf < 2; ++mf) {
                int rowb = mf * 16 + (lq << 2);
                #pragma unroll
                for (int nf = 0; nf < 4; ++nf) {
                    int col = nf * 16 + ln;
                    int ck = col >> 3, cl = col & 7;
                    #pragma unroll
                    for (int r = 0; r < 4; ++r) {
                        float p = __expf(fmaf(sf[mf][nf][r], sc, -SHIFT));
                        if (diag && (j0 + col > wrow0 + rowb + r)) p = 0.f;
                        int row = rowb + r;
                        psw[row * 72 + ((ck ^ (row & 7)) << 3) + cl] = f2bf(p);
                    }
                }
            }

            short8 ap0[2][2];
            #pragma unroll
            for (int mf = 0; mf < 2; ++mf)
                #pragma unroll
                for (int ks = 0; ks < 2; ++ks)
                    ap0[mf][ks] = *(const short8*)(psw + (mf * 16 + ln) * 72 + (((ks * 4 + lq) ^ (ln & 7)) << 3));
            #pragma unroll
            for (int ks = 0; ks < 2; ++ks) {
                lacc[0] = __builtin_amdgcn_mfma_f32_16x16x32_bf16(ap0[0][ks], onesb, lacc[0], 0, 0, 0);
                lacc[1] = __builtin_amdgcn_mfma_f32_16x16x32_bf16(ap0[1][ks], onesb, lacc[1], 0, 0, 0);
                #pragma unroll
                for (int nd = 0; nd < 8; ++nd) {
                    short8 bv = *(const short8*)(VsA + ks * 4096 + (nd * 16 + ln) * 32 + ((lq ^ swz) << 3));
                    o[0][nd] = __builtin_amdgcn_mfma_f32_16x16x32_bf16(ap0[0][ks], bv, o[0][nd], 0, 0, 0);
                    o[1][nd] = __builtin_amdgcn_mfma_f32_16x16x32_bf16(ap0[1][ks], bv, o[1][nd], 0, 0, 0);
                }
            }
        }
        __syncthreads();
    }

    int b = bh >> 4, h = bh & 15;
    #pragma unroll
    for (int mf = 0; mf < 2; ++mf)
        #pragma unroll
        for (int r = 0; r < 4; ++r) {
            float lv = __shfl(lacc[mf][r], lane & 48, 64);
            float inv = 1.0f / lv;
            int q = wrow0 + mf * 16 + (lq << 2) + r;
            u16* cp = ctx + (((size_t)(b * Sc + q)) * Hc + h) * HDc + ln;
            #pragma unroll
            for (int nd = 0; nd < 8; ++nd)
                cp[nd * 16] = f2bf(o[mf][nd][r] * inv);
        }
}

extern "C" void kernel_launch(void* const* d_in, const int* in_sizes, int n_in,
                              void* d_out, int out_size, void* d_ws, size_t ws_size,
                              hipStream_t stream) {
    (void)in_sizes; (void)n_in; (void)out_size; (void)ws_size;
    const float* x  = (const float*)d_in[0];
    const float* Wq = (const float*)d_in[2];
    const float* Wk = (const float*)d_in[3];
    const float* Wv = (const float*)d_in[4];
    const float* Wo = (const float*)d_in[5];

    char* w = (char*)d_ws;
    u16* Wt  = (u16*)w; w += (size_t)3 * Dc * Dc * 2;
    u16* Qb  = (u16*)w; w += (size_t)Bc * Hc * Sc * HDc * 2;
    u16* Kb  = (u16*)w; w += (size_t)Bc * Hc * Sc * HDc * 2;
    u16* Vb  = (u16*)w; w += (size_t)Bc * Hc * Sc * HDc * 2;
    u16* ctx = (u16*)w; w += (size_t)Bc * Sc * Hc * HDc * 2;
    float* ctab = (float*)w; w += (size_t)Sc * 64 * 4;
    float* stab = (float*)w; w += (size_t)Sc * 64 * 4;
    u16* xb = (u16*)d_out;

    rope_tab_k<<<dim3(Sc * 64 / 256), 256, 0, stream>>>(ctab, stab);

    int nx = Bc * Sc * Dc;
    cvt_k<<<dim3(nx / 2048), 256, 0, stream>>>(x, xb, nx);

    tcvt3_k<<<dim3(Dc / 64, Dc / 64, 3), 256, 0, stream>>>(Wq, Wk, Wv, Wt, Dc, Dc);
    gemm128_qkv<<<dim3(3 * Dc / 256, (Bc * Sc) / 128), 512, 0, stream>>>(
        xb, Wt, Qb, Kb, Vb, ctab, stab);

    fattn_k<<<dim3(Bc * Hc, Sc / 128), 256, 0, stream>>>(Qb, Kb, Vb, ctx);

    tcvt3_k<<<dim3(Dc / 64, Dc / 64, 1), 256, 0, stream>>>(Wo, Wo, Wo, Wt, Dc, Dc);
    gemm_bt<2><<<dim3(Dc / 128, (Bc * Sc) / 128), 256, 0, stream>>>(
        ctx, Wt, (float*)d_out, Bc * Sc, Dc, Dc);
}

// Round 4
// 406.088 us; speedup vs baseline: 1.0847x; 1.0445x over previous
//
#include <hip/hip_runtime.h>

typedef unsigned short u16;
typedef unsigned int u32;

constexpr int Bc = 2, Sc = 2048, Dc = 2048, Hc = 16, HDc = 128;

using short8 = __attribute__((ext_vector_type(8))) short;
using f32x4v = __attribute__((ext_vector_type(4))) float;

static __device__ __forceinline__ float bf2f(u16 v) { return __uint_as_float(((u32)v) << 16); }
static __device__ __forceinline__ u16 f2bf(float f) {
    u32 u = __float_as_uint(f);
    return (u16)((u + 0x7fffu + ((u >> 16) & 1u)) >> 16);
}

// async global->LDS, 16B per lane; LDS dest = wave-uniform base + lane*16
__device__ __forceinline__ void gll16(const u16* g, u16* l) {
    __builtin_amdgcn_global_load_lds((const __attribute__((address_space(1))) void*)g,
                                     (__attribute__((address_space(3))) void*)l, 16, 0, 0);
}

#define FENCE asm volatile("" ::: "memory")

// ---------------- RoPE cos/sin tables: [S][64] fp32 ----------------
__global__ __launch_bounds__(256) void rope_tab_k(float* __restrict__ ctab, float* __restrict__ stab) {
    int idx = blockIdx.x * 256 + threadIdx.x; // S*64 threads
    int s = idx >> 6, i = idx & 63;
    float freq = exp2f(-(float)i * 0.20762050593045952f); // 10000^(-i/64)
    float ang = (float)s * freq;
    float c, sn;
    sincosf(ang, &sn, &c);
    ctab[idx] = c;
    stab[idx] = sn;
}

// ---------------- fp32 -> bf16 bulk convert ----------------
__global__ __launch_bounds__(256) void cvt_k(const float* __restrict__ in, u16* __restrict__ out, int n) {
    int i = (blockIdx.x * 256 + threadIdx.x) * 8;
    if (i >= n) return;
    float4 a = *(const float4*)(in + i);
    float4 b = *(const float4*)(in + i + 4);
    u16 r[8] = {f2bf(a.x), f2bf(a.y), f2bf(a.z), f2bf(a.w),
                f2bf(b.x), f2bf(b.y), f2bf(b.z), f2bf(b.w)};
    *(uint4*)(out + i) = *(uint4*)r;
}

// ---------------- fp32 W (R x C) -> bf16 Wt (C x R), 64x64 tiles; z selects source ----------------
__global__ __launch_bounds__(256) void tcvt3_k(const float* __restrict__ in0, const float* __restrict__ in1,
                                               const float* __restrict__ in2, u16* __restrict__ out,
                                               int R, int C) {
    __shared__ u16 tile[64][68];
    const float* in = (blockIdx.z == 0) ? in0 : (blockIdx.z == 1) ? in1 : in2;
    u16* o = out + (size_t)blockIdx.z * R * C;
    int bx = blockIdx.x * 64, by = blockIdx.y * 64;
    int t = threadIdx.x;
    int r = t >> 4, c4 = (t & 15) * 4;
    #pragma unroll
    for (int i = 0; i < 4; ++i) {
        int row = by + r + i * 16;
        float4 v = *(const float4*)(in + (size_t)row * C + bx + c4);
        u16* d = &tile[r + i * 16][c4];
        d[0] = f2bf(v.x); d[1] = f2bf(v.y); d[2] = f2bf(v.z); d[3] = f2bf(v.w);
    }
    __syncthreads();
    int oc = t >> 4, r4 = (t & 15) * 4;
    #pragma unroll
    for (int i = 0; i < 4; ++i) {
        int orow = oc + i * 16;
        u16 v[4] = {tile[r4][orow], tile[r4 + 1][orow], tile[r4 + 2][orow], tile[r4 + 3][orow]};
        *(uint2*)&o[(size_t)(bx + orow) * R + by + r4] = *(const uint2*)v;
    }
}

// ================= QKV GEMM: 128x256, BK=32, 2-buffer, 2 blocks/CU ==================
// A: M x K bf16 (4096 x 2048); Bt: N x K bf16 (6144 = [WqT;WkT;WvT]).
// 768 blocks, 3 per CU with 2 co-resident: cross-block TLP hides vmcnt/barrier stalls.
// Fused epilogue: n<2048 -> Q (+RoPE), <4096 -> K (+RoPE), else V^T (B,H,HD,S).
__global__ __launch_bounds__(512, 4) void gemm_qkv32(
        const u16* __restrict__ A, const u16* __restrict__ Bt,
        u16* __restrict__ Oq, u16* __restrict__ Ok, u16* __restrict__ Ov,
        const float* __restrict__ ctab, const float* __restrict__ stab) {
    __shared__ u16 SM[33024]; // 66 KB: staging 48KB (2 x {A 8KB, B 16KB}); epilogue 128x258
    constexpr int K = Dc;     // 2048 -> 64 K-tiles of 32
    int t = threadIdx.x, wid = t >> 6, lane = t & 63;
    int wm = wid >> 2, wn = wid & 3;          // 2 x 4 wave grid; wave tile 64 x 64
    int ln = lane & 15, lq = lane >> 4;

    // XCD-aware bijective swizzle (nwg = 768)
    int nx = gridDim.x; // 24
    int lin = blockIdx.y * nx + blockIdx.x;
    int cpx = (nx * gridDim.y) >> 3; // 96
    int swzb = (lin & 7) * cpx + (lin >> 3);
    int n0 = (swzb % nx) << 8;
    int m0 = (swzb / nx) << 7;

    // buffer b: A at b*12288 (128x32), B at b*12288+4096 (256x32), u16 units
    // row layout 64B = 4 chunks of 16B; stored chunk slot cs holds global chunk cs^((row>>1)&3)
    auto stageAB = [&](int kt, int b) {
        u16* Ad = SM + b * 12288;
        u16* Bd = SM + b * 12288 + 4096;
        {
            int ci = t; // 0..511, A 128x32
            gll16(A + (size_t)(m0 + (ci >> 2)) * K + kt * 32 + (((ci & 3) ^ ((ci >> 3) & 3)) << 3),
                  Ad + (wid * 64) * 8);
        }
        #pragma unroll
        for (int L = 0; L < 2; ++L) {
            int ci = L * 512 + t; // B 256x32
            gll16(Bt + (size_t)(n0 + (ci >> 2)) * K + kt * 32 + (((ci & 3) ^ ((ci >> 3) & 3)) << 3),
                  Bd + (L * 512 + wid * 64) * 8);
        }
    };

    int co = ((lq ^ ((ln >> 1) & 3)) << 3); // read chunk slot (wm*64, mf*16 are 0 mod 8 rows)
    f32x4v acc[4][4] = {};

    auto body = [&](const u16* Ab, const u16* Bb) {
        short8 aF[4], bF[4];
        #pragma unroll
        for (int m = 0; m < 4; ++m)
            aF[m] = *(const short8*)(Ab + (wm * 64 + m * 16 + ln) * 32 + co);
        #pragma unroll
        for (int n = 0; n < 4; ++n)
            bF[n] = *(const short8*)(Bb + (wn * 64 + n * 16 + ln) * 32 + co);
        __builtin_amdgcn_s_setprio(1);
        #pragma unroll
        for (int m = 0; m < 4; ++m)
            #pragma unroll
            for (int n = 0; n < 4; ++n)
                acc[m][n] = __builtin_amdgcn_mfma_f32_16x16x32_bf16(aF[m], bF[n], acc[m][n], 0, 0, 0);
        __builtin_amdgcn_s_setprio(0);
    };

    stageAB(0, 0);
    __syncthreads(); // full drain: buf0 resident for all waves

    #pragma unroll 1
    for (int kt = 0; kt < 64; kt += 2) {
        stageAB(kt + 1, 1);                     // issue next-tile loads early
        body(SM, SM + 4096);                    // compute kt from buf0
        __syncthreads();                        // drain: buf1 resident
        if (kt + 2 < 64) stageAB(kt + 2, 0);
        body(SM + 12288, SM + 16384);           // compute kt+1 from buf1
        __syncthreads();                        // drain: buf0 resident (or epilogue safety)
    }

    // ---- epilogue: 128 x 258 bf16 LDS strip, then coalesced fused writes ----
    int which = n0 >> 11;            // 0=Q,1=K,2=V
    int h0 = (n0 & 2047) >> 7;       // tile covers heads h0, h0+1
    int b_ = m0 >> 11;
    int s0 = m0 & (Sc - 1);
    u16* Es = SM;
    const int ESTR = 258;

    #pragma unroll
    for (int mf = 0; mf < 4; ++mf)
        #pragma unroll
        for (int nf = 0; nf < 4; ++nf)
            #pragma unroll
            for (int r = 0; r < 4; ++r)
                Es[(wm * 64 + mf * 16 + (lq << 2) + r) * ESTR + wn * 64 + nf * 16 + ln] =
                    f2bf(acc[mf][nf][r]);
    __syncthreads();

    if (which < 2) {
        // Q or K: +RoPE. thread t: (head-half hh, row r) from t>>1, half h2=t&1.
        u16* dst0 = which ? Ok : Oq;
        int u = t >> 1, h2 = t & 1;
        int r = u & 127, hh = u >> 7;
        int s = s0 + r;
        const u16* rowp = Es + r * ESTR + hh * 128;
        const float* ct = ctab + (size_t)s * 64;
        const float* st = stab + (size_t)s * 64;
        u16* dp = dst0 + (((size_t)(b_ * Hc + h0 + hh)) * Sc + s) * HDc + h2 * 64;
        #pragma unroll
        for (int j8 = 0; j8 < 64; j8 += 8) {
            uint4 aa = *(const uint4*)(rowp + j8);
            uint4 bb = *(const uint4*)(rowp + 64 + j8);
            const u16* ap8 = (const u16*)&aa;
            const u16* bp8 = (const u16*)&bb;
            float4 c0f = *(const float4*)(ct + j8);
            float4 c1f = *(const float4*)(ct + j8 + 4);
            float4 sn0 = *(const float4*)(st + j8);
            float4 sn1 = *(const float4*)(st + j8 + 4);
            float cc[8] = {c0f.x, c0f.y, c0f.z, c0f.w, c1f.x, c1f.y, c1f.z, c1f.w};
            float ss[8] = {sn0.x, sn0.y, sn0.z, sn0.w, sn1.x, sn1.y, sn1.z, sn1.w};
            u16 ov[8];
            #pragma unroll
            for (int e = 0; e < 8; ++e) {
                float x1 = bf2f(ap8[e]), x2 = bf2f(bp8[e]);
                ov[e] = h2 ? f2bf(x2 * cc[e] + x1 * ss[e]) : f2bf(x1 * cc[e] - x2 * ss[e]);
            }
            *(uint4*)(dp + j8) = *(const uint4*)ov;
        }
    } else {
        // V^T: thread t: (head-half hh, col d) from t>>1, s-half sh=t&1.
        int u = t >> 1, sh = t & 1;
        int d = u & 127, hh = u >> 7;
        u16* dp = Ov + (((size_t)(b_ * Hc + h0 + hh)) * HDc + d) * Sc + s0 + sh * 64;
        #pragma unroll
        for (int r8 = 0; r8 < 64; r8 += 8) {
            u16 ov[8];
            #pragma unroll
            for (int e = 0; e < 8; ++e)
                ov[e] = Es[(sh * 64 + r8 + e) * ESTR + hh * 128 + d];
            *(uint4*)(dp + r8) = *(const uint4*)ov;
        }
    }
}

// ================= out-proj GEMM: 128x256 BK=64 8-wave triple-buffer ================
// A = ctx bf16 (4096 x 2048), Bt = Wo^T bf16 (2048 x 2048), C2 fp32 (4096 x 2048).
// grid 8 x 32 = 256 blocks = exactly 1 round of 256 CUs.

#define RDA8(P) do { _Pragma("unroll") for (int m_ = 0; m_ < 4; ++m_) { \
    aF[m_][0] = *(const short8*)((P) + m_ * 1024 + co0); \
    aF[m_][1] = *(const short8*)((P) + m_ * 1024 + co1); } } while (0)

#define RDB2(P, nh) do { _Pragma("unroll") for (int j_ = 0; j_ < 2; ++j_) { \
    bF[j_][0] = *(const short8*)((P) + ((nh) * 2 + j_) * 1024 + co0); \
    bF[j_][1] = *(const short8*)((P) + ((nh) * 2 + j_) * 1024 + co1); } } while (0)

#define MFQ8(nh) do { _Pragma("unroll") for (int m_ = 0; m_ < 4; ++m_) \
    _Pragma("unroll") for (int j_ = 0; j_ < 2; ++j_) { \
    f32x4v& c_ = acc[m_][(nh) * 2 + j_]; \
    c_ = __builtin_amdgcn_mfma_f32_16x16x32_bf16(aF[m_][0], bF[j_][0], c_, 0, 0, 0); \
    c_ = __builtin_amdgcn_mfma_f32_16x16x32_bf16(aF[m_][1], bF[j_][1], c_, 0, 0, 0); } } while (0)

#define PT(nh) do { FENCE; __builtin_amdgcn_s_barrier(); FENCE; \
    asm volatile("s_waitcnt lgkmcnt(0)" ::: "memory"); \
    __builtin_amdgcn_s_setprio(1); MFQ8(nh); __builtin_amdgcn_s_setprio(0); \
    FENCE; __builtin_amdgcn_s_barrier(); FENCE; } while (0)

#define KTILE(aRb, bRb, KST, ADST, BDST, VW) do { \
    RDA8(aRb); RDB2(bRb, 0); \
    if ((KST) >= 0) stageA(KST, ADST); \
    PT(0); \
    RDB2(bRb, 1); \
    if ((KST) >= 0) stageB(KST, BDST); \
    if ((VW) == 6) asm volatile("s_waitcnt vmcnt(6)" ::: "memory"); \
    else if ((VW) == 0) asm volatile("s_waitcnt vmcnt(0)" ::: "memory"); \
    PT(1); } while (0)

__global__ __launch_bounds__(512, 2) void gemm128_op(
        const u16* __restrict__ A, const u16* __restrict__ Bt, float* __restrict__ C2) {
    __shared__ u16 SM[73728]; // 144 KiB: A x3 (16KB each) + B x3 (32KB each)
    constexpr int K = Dc;     // 2048 -> 32 K-tiles of 64
    constexpr int NT = 32;
    constexpr int N = Dc;
    int t = threadIdx.x, wid = t >> 6, lane = t & 63;
    int wm = wid >> 2, wn = wid & 3;          // 2 x 4 wave grid; wave tile 64 x 64
    int ln = lane & 15, lq = lane >> 4;

    // XCD-aware bijective swizzle (nwg = 256)
    int nx = gridDim.x; // 8
    int lin = blockIdx.y * nx + blockIdx.x;
    int cpx = (nx * gridDim.y) >> 3; // 32
    int swzb = (lin & 7) * cpx + (lin >> 3);
    int n0 = (swzb % nx) << 8;
    int m0 = (swzb / nx) << 7;

    u16* As0 = SM;
    u16* As1 = SM + 8192;
    u16* As2 = SM + 16384;
    u16* Bs0 = SM + 24576;
    u16* Bs1 = SM + 40960;
    u16* Bs2 = SM + 57344;

    auto stageA = [&](int kt, u16* dst) {
        #pragma unroll
        for (int L = 0; L < 2; ++L) {
            int ch16 = L * 512 + wid * 64 + lane; // 16B-chunk index, 128x64 tile
            int row = ch16 >> 3, ch = ch16 & 7;
            gll16(A + (size_t)(m0 + row) * K + kt * 64 + ((ch ^ (row & 7)) << 3),
                  dst + (L * 512 + wid * 64) * 8);
        }
    };
    auto stageB = [&](int kt, u16* dst) {
        #pragma unroll
        for (int L = 0; L < 4; ++L) {
            int ch16 = L * 512 + wid * 64 + lane; // 16B-chunk index, 256x64 tile
            int row = ch16 >> 3, ch = ch16 & 7;
            gll16(Bt + (size_t)(n0 + row) * K + kt * 64 + ((ch ^ (row & 7)) << 3),
                  dst + (L * 512 + wid * 64) * 8);
        }
    };

    const u16* aR0 = As0 + (wm * 64 + ln) * 64;
    const u16* aR1 = As1 + (wm * 64 + ln) * 64;
    const u16* aR2 = As2 + (wm * 64 + ln) * 64;
    const u16* bR0 = Bs0 + (wn * 64 + ln) * 64;
    const u16* bR1 = Bs1 + (wn * 64 + ln) * 64;
    const u16* bR2 = Bs2 + (wn * 64 + ln) * 64;
    int sw = ln & 7;
    int co0 = (lq ^ sw) << 3;        // k-slice 0 chunk (swizzled), u16 units
    int co1 = ((4 | lq) ^ sw) << 3;  // k-slice 1 chunk

    short8 aF[4][2], bF[2][2];
    f32x4v acc[4][4] = {};

    stageA(0, As0); stageB(0, Bs0);
    stageA(1, As1); stageB(1, Bs1);
    asm volatile("s_waitcnt vmcnt(6)" ::: "memory"); // kt0 resident, kt1 in flight
    FENCE; __builtin_amdgcn_s_barrier(); FENCE;

    for (int k3 = 0; k3 < NT - 2; k3 += 3) {
        KTILE(aR0, bR0, k3 + 2, As2, Bs2, 6);
        KTILE(aR1, bR1, k3 + 3, As0, Bs0, 6);
        KTILE(aR2, bR2, k3 + 4, As1, Bs1, 6);
    }
    KTILE(aR0, bR0, -1, As0, Bs0, 0);  // kt=30; drain so kt31 resident
    KTILE(aR1, bR1, -1, As0, Bs0, -1); // kt=31

    int rb = m0 + wm * 64 + (lq << 2);
    int cb = n0 + wn * 64 + ln;
    #pragma unroll
    for (int mf = 0; mf < 4; ++mf)
        #pragma unroll
        for (int nf = 0; nf < 4; ++nf)
            #pragma unroll
            for (int r = 0; r < 4; ++r)
                C2[(size_t)(rb + mf * 16 + r) * N + cb + nf * 16] = acc[mf][nf][r];
}

// ---------------- MFMA flash attention, fixed-shift softmax, swizzled LDS ----------------
__global__ __launch_bounds__(256) void fattn_k(const u16* __restrict__ Q, const u16* __restrict__ K,
                                               const u16* __restrict__ Vt, u16* __restrict__ ctx) {
    __shared__ u16 KsA[8192];
    __shared__ u16 VsA[8192];
    __shared__ u16 PsA[4 * 32 * 72];
    int t = threadIdx.x, wid = t >> 6, lane = t & 63;
    int bh = blockIdx.x;
    int yt = blockIdx.y;
    int qi = (yt < 8) ? yt : 23 - yt;
    int q0 = qi << 7;
    int wrow0 = q0 + wid * 32;
    const u16* Qb = Q + ((size_t)bh * Sc + wrow0) * HDc;
    const u16* Kb = K + (size_t)bh * Sc * HDc;
    const u16* Vb = Vt + (size_t)bh * HDc * Sc;
    int ln = lane & 15, lq = lane >> 4;
    u16* psw = PsA + wid * 32 * 72;

    short8 aq[2][4];
    #pragma unroll
    for (int mf = 0; mf < 2; ++mf)
        #pragma unroll
        for (int ks = 0; ks < 4; ++ks)
            aq[mf][ks] = *(const short8*)(Qb + (size_t)(mf * 16 + ln) * HDc + ks * 32 + lq * 8);

    short8 onesb;
    {
        short v = (ln == 0) ? (short)0x3F80 : (short)0;
        #pragma unroll
        for (int e = 0; e < 8; ++e) onesb[e] = v;
    }

    f32x4v o[2][8] = {};
    f32x4v lacc[2] = {};

    const float sc = 0.08838834764831845f;
    const float SHIFT = 12.0f;
    int jendw = wrow0 + 31;
    int jendb = q0 + 127;
    int swz = (ln >> 1) & 3;

    for (int j0 = 0; j0 <= jendb; j0 += 64) {
        #pragma unroll
        for (int i = 0; i < 4; ++i) {
            int p = (wid * 4 + i) * 64 + lane;
            int plane = p >> 8, key = (p >> 2) & 63;
            int qc = (p & 3) ^ ((key >> 1) & 3);
            gll16(Kb + (size_t)(j0 + key) * HDc + plane * 32 + qc * 8,
                  KsA + (size_t)(wid * 4 + i) * 512);
        }
        #pragma unroll
        for (int i = 0; i < 4; ++i) {
            int p = (wid * 4 + i) * 64 + lane;
            int plane = p >> 9, d = (p >> 2) & 127;
            int qc = (p & 3) ^ ((d >> 1) & 3);
            gll16(Vb + (size_t)d * Sc + j0 + plane * 32 + qc * 8,
                  VsA + (size_t)(wid * 4 + i) * 512);
        }
        __syncthreads();

        if (j0 <= jendw) {
            f32x4v sf[2][4] = {};
            #pragma unroll
            for (int ks = 0; ks < 4; ++ks)
                #pragma unroll
                for (int nf = 0; nf < 4; ++nf) {
                    short8 bk = *(const short8*)(KsA + ks * 2048 + (nf * 16 + ln) * 32 + ((lq ^ swz) << 3));
                    sf[0][nf] = __builtin_amdgcn_mfma_f32_16x16x32_bf16(aq[0][ks], bk, sf[0][nf], 0, 0, 0);
                    sf[1][nf] = __builtin_amdgcn_mfma_f32_16x16x32_bf16(aq[1][ks], bk, sf[1][nf], 0, 0, 0);
                }

            bool diag = (j0 + 63 > wrow0);
            #pragma unroll
            for (int mf = 0; mf < 2; ++mf) {
                int rowb = mf * 16 + (lq << 2);
                #pragma unroll
                for (int nf = 0; nf < 4; ++nf) {
                    int col = nf * 16 + ln;
                    int ck = col >> 3, cl = col & 7;
                    #pragma unroll
                    for (int r = 0; r < 4; ++r) {
                        float p = __expf(fmaf(sf[mf][nf][r], sc, -SHIFT));
                        if (diag && (j0 + col > wrow0 + rowb + r)) p = 0.f;
                        int row = rowb + r;
                        psw[row * 72 + ((ck ^ (row & 7)) << 3) + cl] = f2bf(p);
                    }
                }
            }

            short8 ap0[2][2];
            #pragma unroll
            for (int mf = 0; mf < 2; ++mf)
                #pragma unroll
                for (int ks = 0; ks < 2; ++ks)
                    ap0[mf][ks] = *(const short8*)(psw + (mf * 16 + ln) * 72 + (((ks * 4 + lq) ^ (ln & 7)) << 3));
            #pragma unroll
            for (int ks = 0; ks < 2; ++ks) {
                lacc[0] = __builtin_amdgcn_mfma_f32_16x16x32_bf16(ap0[0][ks], onesb, lacc[0], 0, 0, 0);
                lacc[1] = __builtin_amdgcn_mfma_f32_16x16x32_bf16(ap0[1][ks], onesb, lacc[1], 0, 0, 0);
                #pragma unroll
                for (int nd = 0; nd < 8; ++nd) {
                    short8 bv = *(const short8*)(VsA + ks * 4096 + (nd * 16 + ln) * 32 + ((lq ^ swz) << 3));
                    o[0][nd] = __builtin_amdgcn_mfma_f32_16x16x32_bf16(ap0[0][ks], bv, o[0][nd], 0, 0, 0);
                    o[1][nd] = __builtin_amdgcn_mfma_f32_16x16x32_bf16(ap0[1][ks], bv, o[1][nd], 0, 0, 0);
                }
            }
        }
        __syncthreads();
    }

    int b = bh >> 4, h = bh & 15;
    #pragma unroll
    for (int mf = 0; mf < 2; ++mf)
        #pragma unroll
        for (int r = 0; r < 4; ++r) {
            float lv = __shfl(lacc[mf][r], lane & 48, 64);
            float inv = 1.0f / lv;
            int q = wrow0 + mf * 16 + (lq << 2) + r;
            u16* cp = ctx + (((size_t)(b * Sc + q)) * Hc + h) * HDc + ln;
            #pragma unroll
            for (int nd = 0; nd < 8; ++nd)
                cp[nd * 16] = f2bf(o[mf][nd][r] * inv);
        }
}

extern "C" void kernel_launch(void* const* d_in, const int* in_sizes, int n_in,
                              void* d_out, int out_size, void* d_ws, size_t ws_size,
                              hipStream_t stream) {
    (void)in_sizes; (void)n_in; (void)out_size; (void)ws_size;
    const float* x  = (const float*)d_in[0];
    const float* Wq = (const float*)d_in[2];
    const float* Wk = (const float*)d_in[3];
    const float* Wv = (const float*)d_in[4];
    const float* Wo = (const float*)d_in[5];

    char* w = (char*)d_ws;
    u16* Wt  = (u16*)w; w += (size_t)3 * Dc * Dc * 2;
    u16* Qb  = (u16*)w; w += (size_t)Bc * Hc * Sc * HDc * 2;
    u16* Kb  = (u16*)w; w += (size_t)Bc * Hc * Sc * HDc * 2;
    u16* Vb  = (u16*)w; w += (size_t)Bc * Hc * Sc * HDc * 2;
    u16* ctx = (u16*)w; w += (size_t)Bc * Sc * Hc * HDc * 2;
    float* ctab = (float*)w; w += (size_t)Sc * 64 * 4;
    float* stab = (float*)w; w += (size_t)Sc * 64 * 4;
    u16* xb = (u16*)d_out;

    rope_tab_k<<<dim3(Sc * 64 / 256), 256, 0, stream>>>(ctab, stab);

    int nx = Bc * Sc * Dc;
    cvt_k<<<dim3(nx / 2048), 256, 0, stream>>>(x, xb, nx);

    tcvt3_k<<<dim3(Dc / 64, Dc / 64, 3), 256, 0, stream>>>(Wq, Wk, Wv, Wt, Dc, Dc);
    gemm_qkv32<<<dim3(3 * Dc / 256, (Bc * Sc) / 128), 512, 0, stream>>>(
        xb, Wt, Qb, Kb, Vb, ctab, stab);

    fattn_k<<<dim3(Bc * Hc, Sc / 128), 256, 0, stream>>>(Qb, Kb, Vb, ctx);

    tcvt3_k<<<dim3(Dc / 64, Dc / 64, 1), 256, 0, stream>>>(Wo, Wo, Wo, Wt, Dc, Dc);
    gemm128_op<<<dim3(Dc / 256, (Bc * Sc) / 128), 512, 0, stream>>>(
        ctx, Wt, (float*)d_out);
}

// Round 5
// 393.614 us; speedup vs baseline: 1.1191x; 1.0317x over previous
//
#include <hip/hip_runtime.h>

typedef unsigned short u16;
typedef unsigned int u32;

constexpr int Bc = 2, Sc = 2048, Dc = 2048, Hc = 16, HDc = 128;

using short8 = __attribute__((ext_vector_type(8))) short;
using f32x4v = __attribute__((ext_vector_type(4))) float;

static __device__ __forceinline__ float bf2f(u16 v) { return __uint_as_float(((u32)v) << 16); }
static __device__ __forceinline__ u16 f2bf(float f) {
    u32 u = __float_as_uint(f);
    return (u16)((u + 0x7fffu + ((u >> 16) & 1u)) >> 16);
}

// async global->LDS, 16B per lane; LDS dest = wave-uniform base + lane*16
__device__ __forceinline__ void gll16(const u16* g, u16* l) {
    __builtin_amdgcn_global_load_lds((const __attribute__((address_space(1))) void*)g,
                                     (__attribute__((address_space(3))) void*)l, 16, 0, 0);
}

#define FENCE asm volatile("" ::: "memory")

// ---------------- RoPE cos/sin tables: [S][64] fp32 ----------------
__global__ __launch_bounds__(256) void rope_tab_k(float* __restrict__ ctab, float* __restrict__ stab) {
    int idx = blockIdx.x * 256 + threadIdx.x; // S*64 threads
    int s = idx >> 6, i = idx & 63;
    float freq = exp2f(-(float)i * 0.20762050593045952f); // 10000^(-i/64)
    float ang = (float)s * freq;
    float c, sn;
    sincosf(ang, &sn, &c);
    ctab[idx] = c;
    stab[idx] = sn;
}

// ---------------- fp32 -> bf16 bulk convert ----------------
__global__ __launch_bounds__(256) void cvt_k(const float* __restrict__ in, u16* __restrict__ out, int n) {
    int i = (blockIdx.x * 256 + threadIdx.x) * 8;
    if (i >= n) return;
    float4 a = *(const float4*)(in + i);
    float4 b = *(const float4*)(in + i + 4);
    u16 r[8] = {f2bf(a.x), f2bf(a.y), f2bf(a.z), f2bf(a.w),
                f2bf(b.x), f2bf(b.y), f2bf(b.z), f2bf(b.w)};
    *(uint4*)(out + i) = *(uint4*)r;
}

// ---------------- fp32 W (R x C) -> bf16 Wt (C x R), 64x64 tiles; z selects source ----------------
__global__ __launch_bounds__(256) void tcvt3_k(const float* __restrict__ in0, const float* __restrict__ in1,
                                               const float* __restrict__ in2, u16* __restrict__ out,
                                               int R, int C) {
    __shared__ u16 tile[64][68];
    const float* in = (blockIdx.z == 0) ? in0 : (blockIdx.z == 1) ? in1 : in2;
    u16* o = out + (size_t)blockIdx.z * R * C;
    int bx = blockIdx.x * 64, by = blockIdx.y * 64;
    int t = threadIdx.x;
    int r = t >> 4, c4 = (t & 15) * 4;
    #pragma unroll
    for (int i = 0; i < 4; ++i) {
        int row = by + r + i * 16;
        float4 v = *(const float4*)(in + (size_t)row * C + bx + c4);
        u16* d = &tile[r + i * 16][c4];
        d[0] = f2bf(v.x); d[1] = f2bf(v.y); d[2] = f2bf(v.z); d[3] = f2bf(v.w);
    }
    __syncthreads();
    int oc = t >> 4, r4 = (t & 15) * 4;
    #pragma unroll
    for (int i = 0; i < 4; ++i) {
        int orow = oc + i * 16;
        u16 v[4] = {tile[r4][orow], tile[r4 + 1][orow], tile[r4 + 2][orow], tile[r4 + 3][orow]};
        *(uint2*)&o[(size_t)(bx + orow) * R + by + r4] = *(const uint2*)v;
    }
}

// ================= QKV GEMM: 128x384, BK=32, 3-buffer counted-vmcnt =================
// A: M x K bf16 (4096 x 2048); Bt: N x K bf16 (6144 = [WqT;WkT;WvT]).
// 512 blocks = exactly 2 rounds of 256 CUs, 1 block/CU (96 KiB LDS).
// Per K-tile: {10 ds_read | stage(t+2) | vmcnt(4) | bar | lgk0 | 24 MFMA | bar}.
// Epilogue: 3 col-chunks of 128 (each = one head): Q/K +RoPE, V -> V^T (B,H,HD,S).

#define QT(RB, KST, SB, VW) do { \
    short8 aF[4], bF[6]; \
    _Pragma("unroll") for (int m_ = 0; m_ < 4; ++m_) \
        aF[m_] = *(const short8*)((RB) + (wm * 64 + m_ * 16 + ln) * 32 + co); \
    _Pragma("unroll") for (int n_ = 0; n_ < 6; ++n_) \
        bF[n_] = *(const short8*)((RB) + 4096 + (wn * 96 + n_ * 16 + ln) * 32 + co); \
    if ((KST) >= 0) stage((KST), (SB)); \
    if ((VW) == 4) asm volatile("s_waitcnt vmcnt(4)" ::: "memory"); \
    else if ((VW) == 0) asm volatile("s_waitcnt vmcnt(0)" ::: "memory"); \
    FENCE; __builtin_amdgcn_s_barrier(); FENCE; \
    asm volatile("s_waitcnt lgkmcnt(0)" ::: "memory"); \
    __builtin_amdgcn_s_setprio(1); \
    _Pragma("unroll") for (int m_ = 0; m_ < 4; ++m_) \
    _Pragma("unroll") for (int n_ = 0; n_ < 6; ++n_) \
        acc[m_][n_] = __builtin_amdgcn_mfma_f32_16x16x32_bf16(aF[m_], bF[n_], acc[m_][n_], 0, 0, 0); \
    __builtin_amdgcn_s_setprio(0); \
    FENCE; __builtin_amdgcn_s_barrier(); FENCE; \
} while (0)

__global__ __launch_bounds__(512, 2) void gemm_qkv384(
        const u16* __restrict__ A, const u16* __restrict__ Bt,
        u16* __restrict__ Oq, u16* __restrict__ Ok, u16* __restrict__ Ov,
        const float* __restrict__ ctab, const float* __restrict__ stab) {
    __shared__ u16 SM[49152]; // 96 KiB: 3 buffers x {A 128x32 (8KB), B 384x32 (24KB)}
    constexpr int K = Dc;     // 2048 -> 64 K-tiles of 32
    int t = threadIdx.x, wid = t >> 6, lane = t & 63;
    int wm = wid >> 2, wn = wid & 3;          // 2 x 4 wave grid; wave tile 64 x 96
    int ln = lane & 15, lq = lane >> 4;

    // XCD-aware bijective swizzle (nwg = 512 = 8 x 64); n-major chunks per XCD
    int lin = blockIdx.x;
    int swzb = (lin & 7) * 64 + (lin >> 3);
    int n0 = (swzb >> 5) * 384;      // 16 n-cols
    int m0 = (swzb & 31) * 128;      // 32 m-rows

    // stage K-tile kt into buffer b. LDS written LINEARLY by global_load_lds;
    // read-side chunk swizzle (cs ^= (row>>1)&3) realized on the GLOBAL source.
    auto stage = [&](int kt, int b) {
        u16* Ad = SM + b * 16384;
        u16* Bd = SM + b * 16384 + 4096;
        {
            int row = t >> 2, cs = t & 3; // A: 128x32, 512 chunks of 16B
            gll16(A + (size_t)(m0 + row) * K + kt * 32 + ((cs ^ ((row >> 1) & 3)) << 3),
                  Ad + (wid * 64) * 8);
        }
        #pragma unroll
        for (int L = 0; L < 3; ++L) {
            int ci = L * 512 + t;         // B: 384x32, 1536 chunks
            int row = ci >> 2, cs = ci & 3;
            gll16(Bt + (size_t)(n0 + row) * K + kt * 32 + ((cs ^ ((row >> 1) & 3)) << 3),
                  Bd + (L * 512 + wid * 64) * 8);
        }
    };

    int co = ((lq ^ ((ln >> 1) & 3)) << 3); // swizzled read chunk (row bases are 0 mod 8)
    f32x4v acc[4][6] = {};

    // prologue: tiles 0,1 staged; tile0 resident, tile1 in flight
    stage(0, 0);
    stage(1, 1);
    asm volatile("s_waitcnt vmcnt(4)" ::: "memory");
    FENCE; __builtin_amdgcn_s_barrier(); FENCE;

    // main: tiles 0..59 in 3-buffer rotation (stage t+2), then 4-tile tail
    #pragma unroll 1
    for (int k3 = 0; k3 < 60; k3 += 3) {
        QT(SM,          k3 + 2, 2, 4);
        QT(SM + 16384,  k3 + 3, 0, 4);
        QT(SM + 32768,  k3 + 4, 1, 4);
    }
    QT(SM,          62, 2, 4);  // tile 60
    QT(SM + 16384,  63, 0, 4);  // tile 61
    QT(SM + 32768,  -1, 0, 0);  // tile 62 (drain: tile 63 resident)
    QT(SM,          -1, 0, -1); // tile 63

    // ---- epilogue: 3 col-chunks of 128 through a 128 x 130 bf16 strip ----
    int b_ = m0 >> 11;
    int s0 = m0 & (Sc - 1);
    u16* Es = SM;
    const int ESTR = 130;

    for (int c = 0; c < 3; ++c) {
        #pragma unroll
        for (int nf = 0; nf < 6; ++nf) {
            int cg = wn * 96 + nf * 16;
            if ((cg >> 7) == c) {
                int col = cg & 127;
                #pragma unroll
                for (int mf = 0; mf < 4; ++mf)
                    #pragma unroll
                    for (int r = 0; r < 4; ++r)
                        Es[(wm * 64 + mf * 16 + (lq << 2) + r) * ESTR + col + ln] =
                            f2bf(acc[mf][nf][r]);
            }
        }
        __syncthreads();

        int gcol = n0 + c * 128;
        int which = gcol >> 11;          // 0=Q,1=K,2=V
        int h = (gcol & 2047) >> 7;
        if (which < 2) {
            // Q or K +RoPE: thread t -> row rh=t>>2, half h2=t&1, j-half jh=(t>>1)&1
            u16* dst0 = which ? Ok : Oq;
            int rh = t >> 2, h2 = t & 1, jh = (t >> 1) & 1;
            int s = s0 + rh;
            const u16* rowp = Es + rh * ESTR;
            const float* ct = ctab + (size_t)s * 64;
            const float* st = stab + (size_t)s * 64;
            u16* dp = dst0 + (((size_t)(b_ * Hc + h)) * Sc + s) * HDc + h2 * 64;
            #pragma unroll
            for (int j8 = jh * 32; j8 < jh * 32 + 32; j8 += 8) {
                uint4 aa = *(const uint4*)(rowp + j8);
                uint4 bb = *(const uint4*)(rowp + 64 + j8);
                const u16* ap8 = (const u16*)&aa;
                const u16* bp8 = (const u16*)&bb;
                float4 c0f = *(const float4*)(ct + j8);
                float4 c1f = *(const float4*)(ct + j8 + 4);
                float4 sn0 = *(const float4*)(st + j8);
                float4 sn1 = *(const float4*)(st + j8 + 4);
                float cc[8] = {c0f.x, c0f.y, c0f.z, c0f.w, c1f.x, c1f.y, c1f.z, c1f.w};
                float ss[8] = {sn0.x, sn0.y, sn0.z, sn0.w, sn1.x, sn1.y, sn1.z, sn1.w};
                u16 ov[8];
                #pragma unroll
                for (int e = 0; e < 8; ++e) {
                    float x1 = bf2f(ap8[e]), x2 = bf2f(bp8[e]);
                    ov[e] = h2 ? f2bf(x2 * cc[e] + x1 * ss[e]) : f2bf(x1 * cc[e] - x2 * ss[e]);
                }
                *(uint4*)(dp + j8) = *(const uint4*)ov;
            }
        } else {
            // V^T: thread t -> col d=t>>2, s-quarter sh=t&3 (32 rows each)
            int d = t >> 2, sh = t & 3;
            u16* dp = Ov + (((size_t)(b_ * Hc + h)) * HDc + d) * Sc + s0 + sh * 32;
            #pragma unroll
            for (int r8 = 0; r8 < 32; r8 += 8) {
                u16 ov[8];
                #pragma unroll
                for (int e = 0; e < 8; ++e)
                    ov[e] = Es[(sh * 32 + r8 + e) * ESTR + d];
                *(uint4*)(dp + r8) = *(const uint4*)ov;
            }
        }
        __syncthreads();
    }
}

// ================= out-proj GEMM: 128x256 BK=64 8-wave triple-buffer ================
// A = ctx bf16 (4096 x 2048), Bt = Wo^T bf16 (2048 x 2048), C2 fp32 (4096 x 2048).
// grid 8 x 32 = 256 blocks = exactly 1 round of 256 CUs.

#define RDA8(P) do { _Pragma("unroll") for (int m_ = 0; m_ < 4; ++m_) { \
    aF[m_][0] = *(const short8*)((P) + m_ * 1024 + co0); \
    aF[m_][1] = *(const short8*)((P) + m_ * 1024 + co1); } } while (0)

#define RDB2(P, nh) do { _Pragma("unroll") for (int j_ = 0; j_ < 2; ++j_) { \
    bF[j_][0] = *(const short8*)((P) + ((nh) * 2 + j_) * 1024 + co0); \
    bF[j_][1] = *(const short8*)((P) + ((nh) * 2 + j_) * 1024 + co1); } } while (0)

#define MFQ8(nh) do { _Pragma("unroll") for (int m_ = 0; m_ < 4; ++m_) \
    _Pragma("unroll") for (int j_ = 0; j_ < 2; ++j_) { \
    f32x4v& c_ = acc[m_][(nh) * 2 + j_]; \
    c_ = __builtin_amdgcn_mfma_f32_16x16x32_bf16(aF[m_][0], bF[j_][0], c_, 0, 0, 0); \
    c_ = __builtin_amdgcn_mfma_f32_16x16x32_bf16(aF[m_][1], bF[j_][1], c_, 0, 0, 0); } } while (0)

#define PT(nh) do { FENCE; __builtin_amdgcn_s_barrier(); FENCE; \
    asm volatile("s_waitcnt lgkmcnt(0)" ::: "memory"); \
    __builtin_amdgcn_s_setprio(1); MFQ8(nh); __builtin_amdgcn_s_setprio(0); \
    FENCE; __builtin_amdgcn_s_barrier(); FENCE; } while (0)

#define KTILE(aRb, bRb, KST, ADST, BDST, VW) do { \
    RDA8(aRb); RDB2(bRb, 0); \
    if ((KST) >= 0) stageA(KST, ADST); \
    PT(0); \
    RDB2(bRb, 1); \
    if ((KST) >= 0) stageB(KST, BDST); \
    if ((VW) == 6) asm volatile("s_waitcnt vmcnt(6)" ::: "memory"); \
    else if ((VW) == 0) asm volatile("s_waitcnt vmcnt(0)" ::: "memory"); \
    PT(1); } while (0)

__global__ __launch_bounds__(512, 2) void gemm128_op(
        const u16* __restrict__ A, const u16* __restrict__ Bt, float* __restrict__ C2) {
    __shared__ u16 SM[73728]; // 144 KiB: A x3 (16KB each) + B x3 (32KB each)
    constexpr int K = Dc;     // 2048 -> 32 K-tiles of 64
    constexpr int NT = 32;
    constexpr int N = Dc;
    int t = threadIdx.x, wid = t >> 6, lane = t & 63;
    int wm = wid >> 2, wn = wid & 3;          // 2 x 4 wave grid; wave tile 64 x 64
    int ln = lane & 15, lq = lane >> 4;

    // XCD-aware bijective swizzle (nwg = 256)
    int nx = gridDim.x; // 8
    int lin = blockIdx.y * nx + blockIdx.x;
    int cpx = (nx * gridDim.y) >> 3; // 32
    int swzb = (lin & 7) * cpx + (lin >> 3);
    int n0 = (swzb % nx) << 8;
    int m0 = (swzb / nx) << 7;

    u16* As0 = SM;
    u16* As1 = SM + 8192;
    u16* As2 = SM + 16384;
    u16* Bs0 = SM + 24576;
    u16* Bs1 = SM + 40960;
    u16* Bs2 = SM + 57344;

    auto stageA = [&](int kt, u16* dst) {
        #pragma unroll
        for (int L = 0; L < 2; ++L) {
            int ch16 = L * 512 + wid * 64 + lane; // 16B-chunk index, 128x64 tile
            int row = ch16 >> 3, ch = ch16 & 7;
            gll16(A + (size_t)(m0 + row) * K + kt * 64 + ((ch ^ (row & 7)) << 3),
                  dst + (L * 512 + wid * 64) * 8);
        }
    };
    auto stageB = [&](int kt, u16* dst) {
        #pragma unroll
        for (int L = 0; L < 4; ++L) {
            int ch16 = L * 512 + wid * 64 + lane; // 16B-chunk index, 256x64 tile
            int row = ch16 >> 3, ch = ch16 & 7;
            gll16(Bt + (size_t)(n0 + row) * K + kt * 64 + ((ch ^ (row & 7)) << 3),
                  dst + (L * 512 + wid * 64) * 8);
        }
    };

    const u16* aR0 = As0 + (wm * 64 + ln) * 64;
    const u16* aR1 = As1 + (wm * 64 + ln) * 64;
    const u16* aR2 = As2 + (wm * 64 + ln) * 64;
    const u16* bR0 = Bs0 + (wn * 64 + ln) * 64;
    const u16* bR1 = Bs1 + (wn * 64 + ln) * 64;
    const u16* bR2 = Bs2 + (wn * 64 + ln) * 64;
    int sw = ln & 7;
    int co0 = (lq ^ sw) << 3;        // k-slice 0 chunk (swizzled), u16 units
    int co1 = ((4 | lq) ^ sw) << 3;  // k-slice 1 chunk

    short8 aF[4][2], bF[2][2];
    f32x4v acc[4][4] = {};

    stageA(0, As0); stageB(0, Bs0);
    stageA(1, As1); stageB(1, Bs1);
    asm volatile("s_waitcnt vmcnt(6)" ::: "memory"); // kt0 resident, kt1 in flight
    FENCE; __builtin_amdgcn_s_barrier(); FENCE;

    for (int k3 = 0; k3 < NT - 2; k3 += 3) {
        KTILE(aR0, bR0, k3 + 2, As2, Bs2, 6);
        KTILE(aR1, bR1, k3 + 3, As0, Bs0, 6);
        KTILE(aR2, bR2, k3 + 4, As1, Bs1, 6);
    }
    KTILE(aR0, bR0, -1, As0, Bs0, 0);  // kt=30; drain so kt31 resident
    KTILE(aR1, bR1, -1, As0, Bs0, -1); // kt=31

    int rb = m0 + wm * 64 + (lq << 2);
    int cb = n0 + wn * 64 + ln;
    #pragma unroll
    for (int mf = 0; mf < 4; ++mf)
        #pragma unroll
        for (int nf = 0; nf < 4; ++nf)
            #pragma unroll
            for (int r = 0; r < 4; ++r)
                C2[(size_t)(rb + mf * 16 + r) * N + cb + nf * 16] = acc[mf][nf][r];
}

// ---------------- MFMA flash attention, fixed-shift softmax, swizzled LDS ----------------
__global__ __launch_bounds__(256) void fattn_k(const u16* __restrict__ Q, const u16* __restrict__ K,
                                               const u16* __restrict__ Vt, u16* __restrict__ ctx) {
    __shared__ u16 KsA[8192];
    __shared__ u16 VsA[8192];
    __shared__ u16 PsA[4 * 32 * 72];
    int t = threadIdx.x, wid = t >> 6, lane = t & 63;
    int bh = blockIdx.x;
    int yt = blockIdx.y;
    int qi = (yt < 8) ? yt : 23 - yt;
    int q0 = qi << 7;
    int wrow0 = q0 + wid * 32;
    const u16* Qb = Q + ((size_t)bh * Sc + wrow0) * HDc;
    const u16* Kb = K + (size_t)bh * Sc * HDc;
    const u16* Vb = Vt + (size_t)bh * HDc * Sc;
    int ln = lane & 15, lq = lane >> 4;
    u16* psw = PsA + wid * 32 * 72;

    short8 aq[2][4];
    #pragma unroll
    for (int mf = 0; mf < 2; ++mf)
        #pragma unroll
        for (int ks = 0; ks < 4; ++ks)
            aq[mf][ks] = *(const short8*)(Qb + (size_t)(mf * 16 + ln) * HDc + ks * 32 + lq * 8);

    short8 onesb;
    {
        short v = (ln == 0) ? (short)0x3F80 : (short)0;
        #pragma unroll
        for (int e = 0; e < 8; ++e) onesb[e] = v;
    }

    f32x4v o[2][8] = {};
    f32x4v lacc[2] = {};

    const float sc = 0.08838834764831845f;
    const float SHIFT = 12.0f;
    int jendw = wrow0 + 31;
    int jendb = q0 + 127;
    int swz = (ln >> 1) & 3;

    for (int j0 = 0; j0 <= jendb; j0 += 64) {
        #pragma unroll
        for (int i = 0; i < 4; ++i) {
            int p = (wid * 4 + i) * 64 + lane;
            int plane = p >> 8, key = (p >> 2) & 63;
            int qc = (p & 3) ^ ((key >> 1) & 3);
            gll16(Kb + (size_t)(j0 + key) * HDc + plane * 32 + qc * 8,
                  KsA + (size_t)(wid * 4 + i) * 512);
        }
        #pragma unroll
        for (int i = 0; i < 4; ++i) {
            int p = (wid * 4 + i) * 64 + lane;
            int plane = p >> 9, d = (p >> 2) & 127;
            int qc = (p & 3) ^ ((d >> 1) & 3);
            gll16(Vb + (size_t)d * Sc + j0 + plane * 32 + qc * 8,
                  VsA + (size_t)(wid * 4 + i) * 512);
        }
        __syncthreads();

        if (j0 <= jendw) {
            f32x4v sf[2][4] = {};
            #pragma unroll
            for (int ks = 0; ks < 4; ++ks)
                #pragma unroll
                for (int nf = 0; nf < 4; ++nf) {
                    short8 bk = *(const short8*)(KsA + ks * 2048 + (nf * 16 + ln) * 32 + ((lq ^ swz) << 3));
                    sf[0][nf] = __builtin_amdgcn_mfma_f32_16x16x32_bf16(aq[0][ks], bk, sf[0][nf], 0, 0, 0);
                    sf[1][nf] = __builtin_amdgcn_mfma_f32_16x16x32_bf16(aq[1][ks], bk, sf[1][nf], 0, 0, 0);
                }

            bool diag = (j0 + 63 > wrow0);
            #pragma unroll
            for (int mf = 0; mf < 2; ++mf) {
                int rowb = mf * 16 + (lq << 2);
                #pragma unroll
                for (int nf = 0; nf < 4; ++nf) {
                    int col = nf * 16 + ln;
                    int ck = col >> 3, cl = col & 7;
                    #pragma unroll
                    for (int r = 0; r < 4; ++r) {
                        float p = __expf(fmaf(sf[mf][nf][r], sc, -SHIFT));
                        if (diag && (j0 + col > wrow0 + rowb + r)) p = 0.f;
                        int row = rowb + r;
                        psw[row * 72 + ((ck ^ (row & 7)) << 3) + cl] = f2bf(p);
                    }
                }
            }

            short8 ap0[2][2];
            #pragma unroll
            for (int mf = 0; mf < 2; ++mf)
                #pragma unroll
                for (int ks = 0; ks < 2; ++ks)
                    ap0[mf][ks] = *(const short8*)(psw + (mf * 16 + ln) * 72 + (((ks * 4 + lq) ^ (ln & 7)) << 3));
            #pragma unroll
            for (int ks = 0; ks < 2; ++ks) {
                lacc[0] = __builtin_amdgcn_mfma_f32_16x16x32_bf16(ap0[0][ks], onesb, lacc[0], 0, 0, 0);
                lacc[1] = __builtin_amdgcn_mfma_f32_16x16x32_bf16(ap0[1][ks], onesb, lacc[1], 0, 0, 0);
                #pragma unroll
                for (int nd = 0; nd < 8; ++nd) {
                    short8 bv = *(const short8*)(VsA + ks * 4096 + (nd * 16 + ln) * 32 + ((lq ^ swz) << 3));
                    o[0][nd] = __builtin_amdgcn_mfma_f32_16x16x32_bf16(ap0[0][ks], bv, o[0][nd], 0, 0, 0);
                    o[1][nd] = __builtin_amdgcn_mfma_f32_16x16x32_bf16(ap0[1][ks], bv, o[1][nd], 0, 0, 0);
                }
            }
        }
        __syncthreads();
    }

    int b = bh >> 4, h = bh & 15;
    #pragma unroll
    for (int mf = 0; mf < 2; ++mf)
        #pragma unroll
        for (int r = 0; r < 4; ++r) {
            float lv = __shfl(lacc[mf][r], lane & 48, 64);
            float inv = 1.0f / lv;
            int q = wrow0 + mf * 16 + (lq << 2) + r;
            u16* cp = ctx + (((size_t)(b * Sc + q)) * Hc + h) * HDc + ln;
            #pragma unroll
            for (int nd = 0; nd < 8; ++nd)
                cp[nd * 16] = f2bf(o[mf][nd][r] * inv);
        }
}

extern "C" void kernel_launch(void* const* d_in, const int* in_sizes, int n_in,
                              void* d_out, int out_size, void* d_ws, size_t ws_size,
                              hipStream_t stream) {
    (void)in_sizes; (void)n_in; (void)out_size; (void)ws_size;
    const float* x  = (const float*)d_in[0];
    const float* Wq = (const float*)d_in[2];
    const float* Wk = (const float*)d_in[3];
    const float* Wv = (const float*)d_in[4];
    const float* Wo = (const float*)d_in[5];

    char* w = (char*)d_ws;
    u16* Wt  = (u16*)w; w += (size_t)3 * Dc * Dc * 2;
    u16* Qb  = (u16*)w; w += (size_t)Bc * Hc * Sc * HDc * 2;
    u16* Kb  = (u16*)w; w += (size_t)Bc * Hc * Sc * HDc * 2;
    u16* Vb  = (u16*)w; w += (size_t)Bc * Hc * Sc * HDc * 2;
    u16* ctx = (u16*)w; w += (size_t)Bc * Sc * Hc * HDc * 2;
    float* ctab = (float*)w; w += (size_t)Sc * 64 * 4;
    float* stab = (float*)w; w += (size_t)Sc * 64 * 4;
    u16* xb = (u16*)d_out;

    rope_tab_k<<<dim3(Sc * 64 / 256), 256, 0, stream>>>(ctab, stab);

    int nx = Bc * Sc * Dc;
    cvt_k<<<dim3(nx / 2048), 256, 0, stream>>>(x, xb, nx);

    tcvt3_k<<<dim3(Dc / 64, Dc / 64, 3), 256, 0, stream>>>(Wq, Wk, Wv, Wt, Dc, Dc);
    gemm_qkv384<<<dim3(512), 512, 0, stream>>>(xb, Wt, Qb, Kb, Vb, ctab, stab);

    fattn_k<<<dim3(Bc * Hc, Sc / 128), 256, 0, stream>>>(Qb, Kb, Vb, ctx);

    tcvt3_k<<<dim3(Dc / 64, Dc / 64, 1), 256, 0, stream>>>(Wo, Wo, Wo, Wt, Dc, Dc);
    gemm128_op<<<dim3(Dc / 256, (Bc * Sc) / 128), 512, 0, stream>>>(
        ctx, Wt, (float*)d_out);
}